// Round 1
// baseline (315.872 us; speedup 1.0000x reference)
//
#include <hip/hip_runtime.h>
#include <hip/hip_cooperative_groups.h>
#include <cstdint>
#include <cstddef>

namespace cg = cooperative_groups;

#define B_ 2
#define N_ 2048
#define C_ 256
#define H_ 64
#define W_ 176
#define TW 16
#define NTX 11                    // 176/16 tiles per row
#define NYB 32                    // 2-row bands
#define NTILES2 (B_*NYB*NTX)      // 704 tiles (16px x 2row)
#define CAP 1024                  // per-tile list cap
#define SA 260                    // mlp act LDS stride (floats)
#define FS 40                     // feats_t / gw_t row stride (ushort) = 80 B

typedef unsigned short ushort_t;
typedef short bf16x8 __attribute__((ext_vector_type(8)));
typedef float f32x4  __attribute__((ext_vector_type(4)));

__device__ __forceinline__ short f2bf(float f)   // RNE fp32->bf16
{
    unsigned u = __float_as_uint(f);
    return (short)((u + 0x7FFFu + ((u >> 16) & 1u)) >> 16);
}

// ===========================================================================
// FUSED cooperative kernel: phase0 (weight cvt + zero counts) -> grid.sync
//  -> phase1 (MLP blocks 0..255 || bin blocks 256..511) -> grid.sync
//  -> phase2 (splat, all 704 blocks).
// 704 blocks x 256 thr, LDS 46080 B -> 3 blocks/CU (needs 235 CUs resident).
// ===========================================================================

// MFMA accumulate for 4-wave MLP: each wave owns 4 col-tiles of 16.
template<int K>
__device__ __forceinline__ void mfma_acc4(const short* __restrict__ wt,
                                          const float* actIn, f32x4 (&acc)[4],
                                          int wv_, int quad, int ln15)
{
#pragma unroll
    for (int ks = 0; ks < K / 32; ++ks) {
        const int kb = ks * 32 + quad * 8;
        const float4 a0 = *(const float4*)&actIn[ln15 * SA + kb];
        const float4 a1 = *(const float4*)&actIn[ln15 * SA + kb + 4];
        bf16x8 af = { f2bf(a0.x), f2bf(a0.y), f2bf(a0.z), f2bf(a0.w),
                      f2bf(a1.x), f2bf(a1.y), f2bf(a1.z), f2bf(a1.w) };
#pragma unroll
        for (int tt = 0; tt < 4; ++tt) {
            const int n0 = (wv_ * 4 + tt) * 16;
            const bf16x8 bf = *(const bf16x8*)&wt[(size_t)(n0 + ln15) * K + kb];
            acc[tt] = __builtin_amdgcn_mfma_f32_16x16x32_bf16(af, bf, acc[tt], 0, 0, 0);
        }
    }
}

__global__ __launch_bounds__(256, 3)
void fused_kernel(const float* __restrict__ g, const float* __restrict__ intr,
                  const float* __restrict__ w1, const float* __restrict__ b1,
                  const float* __restrict__ w2, const float* __restrict__ b2,
                  const float* __restrict__ w3f, const float* __restrict__ b3,
                  const float* __restrict__ fw1f, const float* __restrict__ fb1,
                  const float* __restrict__ fw2f, const float* __restrict__ fb2,
                  ushort_t* __restrict__ ftb, float* __restrict__ pp,
                  int* __restrict__ counts, ushort_t* __restrict__ lists,
                  short* __restrict__ wt3, short* __restrict__ wt4,
                  short* __restrict__ wt5, float* __restrict__ out)
{
    __shared__ __align__(16) char smem[46080];   // union: MLP 33280 / splat 46080

    const int tid = threadIdx.x;
    const int bid = blockIdx.x;

    // ---------------- phase 0: weight convert (coalesced reads) + zero counts
    {
        const int gid = bid * 256 + tid;         // 0..180223, 163840 elems
        if (gid < NTILES2) counts[gid] = 0;
        if (gid < 163840) {
            if (gid < 32768) {                   // w3f [128][256] -> wt3[n*128+k]
                const int k = gid >> 8, n = gid & 255;
                wt3[n * 128 + k] = f2bf(w3f[gid]);
            } else if (gid < 98304) {            // fw1f [256][256] -> wt4[n*256+k]
                const int e = gid - 32768;
                const int k = e >> 8, n = e & 255;
                wt4[n * 256 + k] = f2bf(fw1f[e]);
            } else {
                const int e = gid - 98304;
                const int k = e >> 8, n = e & 255;
                wt5[n * 256 + k] = f2bf(fw2f[e]);
            }
        }
    }
    cg::this_grid().sync();

    // ---------------- phase 1: MLP (bid<256) || param+bin (256<=bid<512) ----
    const int lane = tid & 63;
    const int wv_  = tid >> 6;                   // 0..3
    const int quad = lane >> 4;
    const int ln15 = lane & 15;

    if (bid < 256) {
        float* A_ = (float*)smem;                // 16 x SA
        float* Bb = A_ + 16 * SA;
        const int row0 = bid * 16;

        if (tid < 224) {
            const int k = tid >> 4, m = tid & 15;
            A_[m * SA + k] = g[(size_t)(row0 + m) * 14 + k];
        }
        __syncthreads();

        {   // L1: 14 -> 64, relu (4 rows/thread)
            const int col = tid & 63;
            const int m0  = (tid >> 6) * 4;
            float acc[4];
            const float bv = b1[col];
#pragma unroll
            for (int r = 0; r < 4; ++r) acc[r] = bv;
#pragma unroll
            for (int k = 0; k < 14; ++k) {
                const float wl = w1[k * 64 + col];
#pragma unroll
                for (int r = 0; r < 4; ++r)
                    acc[r] = fmaf(A_[(m0 + r) * SA + k], wl, acc[r]);
            }
#pragma unroll
            for (int r = 0; r < 4; ++r)
                Bb[(m0 + r) * SA + col] = fmaxf(acc[r], 0.f);
        }
        __syncthreads();

        {   // L2: 64 -> 128, relu (8 rows/thread)
            const int col = tid & 127;
            const int m0  = (tid >> 7) * 8;
            float acc[8];
            const float bv = b2[col];
#pragma unroll
            for (int r = 0; r < 8; ++r) acc[r] = bv;
#pragma unroll 4
            for (int kq = 0; kq < 16; ++kq) {
                float wl[4];
#pragma unroll
                for (int jj = 0; jj < 4; ++jj) wl[jj] = w2[(4 * kq + jj) * 128 + col];
#pragma unroll
                for (int r = 0; r < 8; ++r) {
                    const float4 a4 = *(const float4*)&Bb[(m0 + r) * SA + 4 * kq];
                    acc[r] = fmaf(a4.x, wl[0], acc[r]);
                    acc[r] = fmaf(a4.y, wl[1], acc[r]);
                    acc[r] = fmaf(a4.z, wl[2], acc[r]);
                    acc[r] = fmaf(a4.w, wl[3], acc[r]);
                }
            }
#pragma unroll
            for (int r = 0; r < 8; ++r)
                A_[(m0 + r) * SA + col] = fmaxf(acc[r], 0.f);
        }
        __syncthreads();

        {   // L3: 128 -> 256 MFMA
            f32x4 acc[4];
#pragma unroll
            for (int t = 0; t < 4; ++t) acc[t] = (f32x4){0.f, 0.f, 0.f, 0.f};
            mfma_acc4<128>(wt3, A_, acc, wv_, quad, ln15);
            __syncthreads();
#pragma unroll
            for (int tt = 0; tt < 4; ++tt) {
                const int n = (wv_ * 4 + tt) * 16 + ln15;
                const float bv = b3[n];
#pragma unroll
                for (int r = 0; r < 4; ++r)
                    Bb[(quad * 4 + r) * SA + n] = acc[tt][r] + bv;
            }
        }
        __syncthreads();

        {   // L4: 256 -> 256 MFMA, relu
            f32x4 acc[4];
#pragma unroll
            for (int t = 0; t < 4; ++t) acc[t] = (f32x4){0.f, 0.f, 0.f, 0.f};
            mfma_acc4<256>(wt4, Bb, acc, wv_, quad, ln15);
            __syncthreads();
#pragma unroll
            for (int tt = 0; tt < 4; ++tt) {
                const int n = (wv_ * 4 + tt) * 16 + ln15;
                const float bv = fb1[n];
#pragma unroll
                for (int r = 0; r < 4; ++r)
                    A_[(quad * 4 + r) * SA + n] = fmaxf(acc[tt][r] + bv, 0.f);
            }
        }
        __syncthreads();

        {   // L5: 256 -> 256 MFMA -> global bf16
            f32x4 acc[4];
#pragma unroll
            for (int t = 0; t < 4; ++t) acc[t] = (f32x4){0.f, 0.f, 0.f, 0.f};
            mfma_acc4<256>(wt5, A_, acc, wv_, quad, ln15);
#pragma unroll
            for (int tt = 0; tt < 4; ++tt) {
                const int n = (wv_ * 4 + tt) * 16 + ln15;
                const float bv = fb2[n];
#pragma unroll
                for (int r = 0; r < 4; ++r)
                    ftb[(size_t)(row0 + quad * 4 + r) * 256 + n] =
                        (ushort_t)f2bf(acc[tt][r] + bv);
            }
        }
    } else if (bid < 512) {
        // ---- param + bin: 16 gaussians/block, 16 band-threads x 2 passes ----
        const int i  = (bid - 256) * 16 + (tid >> 4);
        const int j0 = tid & 15;
        const float* gi = g + (size_t)i * 14;
        const float x = gi[0], y = gi[1], z = gi[2];
        const float s5 = gi[5], s6 = gi[6], wgt = gi[12];
        const float k00 = intr[0], k01 = intr[1], k02 = intr[2];
        const float k10 = intr[3], k11 = intr[4], k12 = intr[5];
        const float k20 = intr[6], k21 = intr[7], k22 = intr[8];
        const float projx = k00 * x + k01 * y + k02 * z;
        const float projy = k10 * x + k11 * y + k12 * z;
        const float projz = k20 * x + k21 * y + k22 * z;
        const float inv = 1.f / (projz + 1e-6f);
        const float scale_x = (float)W_ / k02 * 0.5f;
        const float scale_y = (float)H_ / k12 * 0.5f;
        const float px = projx * inv * scale_x;
        const float py = projy * inv * scale_y;
        const bool valid = z > 0.1f;
        const bool inb = (px >= 0.f) && (px < (float)W_) && (py >= 0.f) && (py < (float)H_);
        const bool mask = valid && inb;
        const float sx = fmaxf(s5 * scale_x, 1.f);
        const float sy = fmaxf(s6 * scale_y, 1.f);
        if (j0 == 0) {
            float4* o = (float4*)(pp + (size_t)i * 8);
            o[0] = make_float4(px, py, 1.f / sx, 1.f / sy);
            o[1] = make_float4(wgt, 0.5f * (sx + sy), 0.f, 0.f);
        }
        if (mask) {
            const float rx = 3.f * sx, ry = 3.f * sy;
            const int ymin = max(0, (int)floorf(py - ry));
            const int ymax = min(H_ - 1, (int)ceilf(py + ry));
            const int bmin = ymin >> 1, bmax = ymax >> 1;
            const int tmin = max(0, (int)floorf((px - rx - (float)(TW - 1)) * (1.f / TW)));
            const int tmax = min(NTX - 1, (int)ceilf((px + rx) * (1.f / TW)));
            const int bb = i / N_, n = i - bb * N_;
#pragma unroll
            for (int half = 0; half < 2; ++half) {
                const int band = bmin + j0 + half * 16;
                if (band <= bmax) {
                    for (int t = tmin; t <= tmax; ++t) {
                        const int tile = (bb * NYB + band) * NTX + t;
                        const int slot = atomicAdd(&counts[tile], 1);
                        if (slot < CAP) lists[(size_t)tile * CAP + slot] = (ushort_t)n;
                    }
                }
            }
        }
    }
    cg::this_grid().sync();

    // ---------------- phase 2: splat ----------------------------------------
    ushort_t* const ft_s = (ushort_t*)smem;            // 2 x 256*FS ushort
    ushort_t* const gw_s = ft_s + 2 * 256 * FS;        // 2 x 32*FS ushort
#define FT_(bf) (ft_s + (bf) * (256 * FS))
#define GW_(bf) (gw_s + (bf) * (32 * FS))

    // center-first tile decode
    const int qb = bid;
    const int b  = qb & 1;
    const int t_ = qb >> 1;
    const int yr = t_ / NTX, xr = t_ % NTX;
    const int yh = (yr + 1) >> 1;
    const int yb = (yr & 1) ? (16 - yh) : (16 + yh);
    const int xh = (xr + 1) >> 1;
    const int txi = (xr & 1) ? (5 - xh) : (5 + xh);
    const int tb  = (b * NYB + yb) * NTX + txi;
    const int y0 = yb * 2, x0 = txi * TW;

    const int cnt = min(counts[tb], CAP);
    const ushort_t* mylist = lists + (size_t)tb * CAP;
    const int gs   = tid >> 5;            // phase A gaussian sub-slot (0..7)
    const int px32 = tid & 31;            // phase A pixel (row*16+x)
    const float fy = (float)(y0 + (px32 >> 4));
    const float fx = (float)(x0 + (px32 & 15));
    const int chg = tid >> 4;             // stage: ch group (0..15), 16 ch each
    const int qp  = tid & 15;             // stage: q pair (0..15)
    const int bN = b * N_;

    f32x4 acc[2][4];
#pragma unroll
    for (int mt = 0; mt < 2; ++mt)
#pragma unroll
        for (int nt = 0; nt < 4; ++nt) acc[mt][nt] = (f32x4){0.f, 0.f, 0.f, 0.f};
    float densp = 0.f, uncp = 0.f;

    uint4 ra0, ra1, rb0, rb1;             // staged 16ch x 2 rows
    const int nchunks = (cnt + 31) >> 5;

    if (cnt > 0) {
        const float4* pv = (const float4*)pp;
        {   // prefetch chunk 0 rows
            const int n0 = mylist[min(2 * qp, cnt - 1)];
            const int n1 = mylist[min(2 * qp + 1, cnt - 1)];
            const uint4* f0 = (const uint4*)(ftb + ((size_t)(bN + n0) << 8) + chg * 16);
            const uint4* f1 = (const uint4*)(ftb + ((size_t)(bN + n1) << 8) + chg * 16);
            ra0 = f0[0]; ra1 = f0[1];
            rb0 = f1[0]; rb1 = f1[1];
        }
        for (int c = 0; c < nchunks; ++c) {
            const int buf = c & 1;
            // ---- phase A: 4 gw per thread -> gw_t[buf] (bf16) ----
#pragma unroll
            for (int jj = 0; jj < 4; ++jj) {
                const int q = 8 * jj + gs;
                const int qi = c * 32 + q;
                const int n = mylist[min(qi, cnt - 1)];
                const float4 e0 = pv[(size_t)(bN + n) * 2 + 0];
                const float4 e1 = pv[(size_t)(bN + n) * 2 + 1];
                const float dyn = (fy - e0.y) * e0.w;
                const float dxn = (fx - e0.x) * e0.z;
                const float dist = dyn * dyn + dxn * dxn;
                float gv = 0.f;
                if (dist < 9.f) gv = __expf(-0.5f * dist) * e1.x;
                if (qi >= cnt) gv = 0.f;
                GW_(buf)[px32 * FS + q] = (ushort_t)f2bf(gv);
                densp += gv;
                uncp  += gv * e1.y;
            }
            // ---- stage: transpose regs -> feats_t[buf][ch][k] ----
            {
                uint* dst = (uint*)FT_(buf);
#pragma unroll
                for (int jj = 0; jj < 4; ++jj) {
                    const uint u0 = (&ra0.x)[jj], v0 = (&rb0.x)[jj];
                    const int ch = chg * 16 + 2 * jj;
                    dst[ch * (FS / 2) + qp]       = (u0 & 0xffffu) | (v0 << 16);
                    dst[(ch + 1) * (FS / 2) + qp] = (u0 >> 16) | (v0 & 0xffff0000u);
                }
#pragma unroll
                for (int jj = 0; jj < 4; ++jj) {
                    const uint u0 = (&ra1.x)[jj], v0 = (&rb1.x)[jj];
                    const int ch = chg * 16 + 8 + 2 * jj;
                    dst[ch * (FS / 2) + qp]       = (u0 & 0xffffu) | (v0 << 16);
                    dst[(ch + 1) * (FS / 2) + qp] = (u0 >> 16) | (v0 & 0xffff0000u);
                }
            }
            __syncthreads();
            // ---- prefetch chunk c+1 rows (overlaps phase B) ----
            if (c + 1 < nchunks) {
                const int q0 = (c + 1) * 32 + 2 * qp;
                const int n0 = mylist[min(q0, cnt - 1)];
                const int n1 = mylist[min(q0 + 1, cnt - 1)];
                const uint4* f0 = (const uint4*)(ftb + ((size_t)(bN + n0) << 8) + chg * 16);
                const uint4* f1 = (const uint4*)(ftb + ((size_t)(bN + n1) << 8) + chg * 16);
                ra0 = f0[0]; ra1 = f0[1];
                rb0 = f1[0]; rb1 = f1[1];
            }
            // ---- phase B: 8 MFMA per wave ----
            bf16x8 af[2];
#pragma unroll
            for (int mt = 0; mt < 2; ++mt)
                af[mt] = *(const bf16x8*)&GW_(buf)[(mt * 16 + ln15) * FS + quad * 8];
#pragma unroll
            for (int nt = 0; nt < 4; ++nt) {
                const int ch0 = wv_ * 64 + nt * 16;
                const bf16x8 bff = *(const bf16x8*)&FT_(buf)[(ch0 + ln15) * FS + quad * 8];
                acc[0][nt] = __builtin_amdgcn_mfma_f32_16x16x32_bf16(af[0], bff, acc[0][nt], 0, 0, 0);
                acc[1][nt] = __builtin_amdgcn_mfma_f32_16x16x32_bf16(af[1], bff, acc[1][nt], 0, 0, 0);
            }
        }
    }

    // ---- density / uncertainty reduction over 8 gs-groups ----
    __syncthreads();
    float* red_d = (float*)ft_s;          // 8 x 36
    float* red_u = red_d + 8 * 36;
    red_d[gs * 36 + px32] = densp;
    red_u[gs * 36 + px32] = uncp;
    __syncthreads();
    for (int s = 4; s > 0; s >>= 1) {
        if (gs < s) {
            red_d[gs * 36 + px32] += red_d[(gs + s) * 36 + px32];
            red_u[gs * 36 + px32] += red_u[(gs + s) * 36 + px32];
        }
        __syncthreads();
    }

    if (tid < 32) {
        const int yy = y0 + (tid >> 4), xx = x0 + (tid & 15);
        const size_t pix = ((size_t)b * H_ + yy) * W_ + xx;
        float* unc_o = out + (size_t)B_ * C_ * H_ * W_;
        float* den_o = unc_o + (size_t)B_ * H_ * W_;
        const float d = fmaxf(red_d[tid], 1e-6f);
        unc_o[pix] = red_u[tid] / d;
        den_o[pix] = d;
    }

    // ---- feature stores: lane = ch (ln15), 4 consecutive x per acc ----
#pragma unroll
    for (int mt = 0; mt < 2; ++mt) {
        const int pxb = mt * 16 + quad * 4;
        float rinv[4];
#pragma unroll
        for (int r = 0; r < 4; ++r)
            rinv[r] = 1.f / fmaxf(red_d[pxb + r], 1e-6f);
        const int yy = y0 + mt;
#pragma unroll
        for (int nt = 0; nt < 4; ++nt) {
            const int ch = wv_ * 64 + nt * 16 + ln15;
            float4 v;
            v.x = acc[mt][nt][0] * rinv[0];
            v.y = acc[mt][nt][1] * rinv[1];
            v.z = acc[mt][nt][2] * rinv[2];
            v.w = acc[mt][nt][3] * rinv[3];
            *(float4*)(out + (((size_t)b * C_ + ch) * H_ + yy) * W_
                       + x0 + quad * 4) = v;
        }
    }
#undef FT_
#undef GW_
}

// ===========================================================================
// FALLBACK path: proven 3-kernel pipeline (unchanged from previous session).
// ===========================================================================
__global__ __launch_bounds__(256)
void prep_kernel(const float* __restrict__ w3f, const float* __restrict__ fw1f,
                 const float* __restrict__ fw2f,
                 short* __restrict__ wt3, short* __restrict__ wt4,
                 short* __restrict__ wt5, int* __restrict__ counts)
{
    const int gid = blockIdx.x * 256 + threadIdx.x;
    if (gid < NTILES2) counts[gid] = 0;
    for (int e = gid; e < 163840; e += 65536) {
        if (e < 32768) {
            const int i = e;
            wt3[i] = f2bf(w3f[(i & 127) * 256 + (i >> 7)]);
        } else if (e < 98304) {
            const int i = e - 32768;
            wt4[i] = f2bf(fw1f[(i & 255) * 256 + (i >> 8)]);
        } else {
            const int i = e - 98304;
            wt5[i] = f2bf(fw2f[(i & 255) * 256 + (i >> 8)]);
        }
    }
}

template<int K>
__device__ __forceinline__ void mfma_acc(const short* __restrict__ wt,
                                         const float* actIn, f32x4 (&acc)[2],
                                         int wv_, int quad, int ln15)
{
#pragma unroll
    for (int ks = 0; ks < K / 32; ++ks) {
        const int kb = ks * 32 + quad * 8;
        const float4 a0 = *(const float4*)&actIn[ln15 * SA + kb];
        const float4 a1 = *(const float4*)&actIn[ln15 * SA + kb + 4];
        bf16x8 af = { f2bf(a0.x), f2bf(a0.y), f2bf(a0.z), f2bf(a0.w),
                      f2bf(a1.x), f2bf(a1.y), f2bf(a1.z), f2bf(a1.w) };
#pragma unroll
        for (int tt = 0; tt < 2; ++tt) {
            const int n0 = (wv_ * 2 + tt) * 16;
            const bf16x8 bf = *(const bf16x8*)&wt[(size_t)(n0 + ln15) * K + kb];
            acc[tt] = __builtin_amdgcn_mfma_f32_16x16x32_bf16(af, bf, acc[tt], 0, 0, 0);
        }
    }
}

__global__ __launch_bounds__(512)
void pb_mlp_kernel(const float* __restrict__ g, const float* __restrict__ intr,
                   const float* __restrict__ w1, const float* __restrict__ b1,
                   const float* __restrict__ w2, const float* __restrict__ b2,
                   const short* __restrict__ wt3, const float* __restrict__ b3,
                   const short* __restrict__ wt4, const float* __restrict__ fb1,
                   const short* __restrict__ wt5, const float* __restrict__ fb2,
                   ushort_t* __restrict__ ftb,
                   float* __restrict__ pp, int* __restrict__ counts,
                   ushort_t* __restrict__ lists)
{
    __shared__ __align__(16) float A_[16 * SA];
    __shared__ __align__(16) float Bb[16 * SA];
    const int tid = threadIdx.x;

    if (blockIdx.x < 256) {
        const int row0 = blockIdx.x * 16;
        const int lane = tid & 63;
        const int wv_  = tid >> 6;
        const int quad = lane >> 4;
        const int ln15 = lane & 15;

        if (tid < 224) {
            const int k = tid / 16, m = tid % 16;
            A_[m * SA + k] = g[(size_t)(row0 + m) * 14 + k];
        }
        __syncthreads();

        {
            const int col = tid & 63;
            const int m0  = (tid >> 6) * 2;
            float acc[2];
            const float bv = b1[col];
            acc[0] = bv; acc[1] = bv;
#pragma unroll
            for (int k = 0; k < 14; ++k) {
                const float wv = w1[k * 64 + col];
                acc[0] = fmaf(A_[(m0 + 0) * SA + k], wv, acc[0]);
                acc[1] = fmaf(A_[(m0 + 1) * SA + k], wv, acc[1]);
            }
            Bb[(m0 + 0) * SA + col] = fmaxf(acc[0], 0.f);
            Bb[(m0 + 1) * SA + col] = fmaxf(acc[1], 0.f);
        }
        __syncthreads();

        {
            const int col = tid & 127;
            const int m0  = (tid >> 7) * 4;
            float acc[4];
            const float bv = b2[col];
#pragma unroll
            for (int r = 0; r < 4; ++r) acc[r] = bv;
#pragma unroll 4
            for (int kq = 0; kq < 16; ++kq) {
                float wv[4];
#pragma unroll
                for (int jj = 0; jj < 4; ++jj) wv[jj] = w2[(4 * kq + jj) * 128 + col];
#pragma unroll
                for (int r = 0; r < 4; ++r) {
                    const float4 a4 = *(const float4*)&Bb[(m0 + r) * SA + 4 * kq];
                    acc[r] = fmaf(a4.x, wv[0], acc[r]);
                    acc[r] = fmaf(a4.y, wv[1], acc[r]);
                    acc[r] = fmaf(a4.z, wv[2], acc[r]);
                    acc[r] = fmaf(a4.w, wv[3], acc[r]);
                }
            }
#pragma unroll
            for (int r = 0; r < 4; ++r)
                A_[(m0 + r) * SA + col] = fmaxf(acc[r], 0.f);
        }
        __syncthreads();

        {
            f32x4 acc[2] = {{0,0,0,0},{0,0,0,0}};
            mfma_acc<128>(wt3, A_, acc, wv_, quad, ln15);
            __syncthreads();
#pragma unroll
            for (int tt = 0; tt < 2; ++tt) {
                const int n = (wv_ * 2 + tt) * 16 + ln15;
                const float bv = b3[n];
#pragma unroll
                for (int r = 0; r < 4; ++r)
                    Bb[(quad * 4 + r) * SA + n] = acc[tt][r] + bv;
            }
        }
        __syncthreads();

        {
            f32x4 acc[2] = {{0,0,0,0},{0,0,0,0}};
            mfma_acc<256>(wt4, Bb, acc, wv_, quad, ln15);
            __syncthreads();
#pragma unroll
            for (int tt = 0; tt < 2; ++tt) {
                const int n = (wv_ * 2 + tt) * 16 + ln15;
                const float bv = fb1[n];
#pragma unroll
                for (int r = 0; r < 4; ++r)
                    A_[(quad * 4 + r) * SA + n] = fmaxf(acc[tt][r] + bv, 0.f);
            }
        }
        __syncthreads();

        {
            f32x4 acc[2] = {{0,0,0,0},{0,0,0,0}};
            mfma_acc<256>(wt5, A_, acc, wv_, quad, ln15);
#pragma unroll
            for (int tt = 0; tt < 2; ++tt) {
                const int n = (wv_ * 2 + tt) * 16 + ln15;
                const float bv = fb2[n];
#pragma unroll
                for (int r = 0; r < 4; ++r)
                    ftb[(size_t)(row0 + quad * 4 + r) * 256 + n] =
                        (ushort_t)f2bf(acc[tt][r] + bv);
            }
        }
        return;
    }

    const int i = (blockIdx.x - 256) * 16 + (tid >> 5);
    const int j = tid & 31;
    const float* gi = g + (size_t)i * 14;
    const float x = gi[0], y = gi[1], z = gi[2];
    const float s5 = gi[5], s6 = gi[6], wv = gi[12];
    const float k00 = intr[0], k01 = intr[1], k02 = intr[2];
    const float k10 = intr[3], k11 = intr[4], k12 = intr[5];
    const float k20 = intr[6], k21 = intr[7], k22 = intr[8];
    const float projx = k00 * x + k01 * y + k02 * z;
    const float projy = k10 * x + k11 * y + k12 * z;
    const float projz = k20 * x + k21 * y + k22 * z;
    const float inv = 1.f / (projz + 1e-6f);
    const float scale_x = (float)W_ / k02 * 0.5f;
    const float scale_y = (float)H_ / k12 * 0.5f;
    const float px = projx * inv * scale_x;
    const float py = projy * inv * scale_y;
    const bool valid = z > 0.1f;
    const bool inb = (px >= 0.f) && (px < (float)W_) && (py >= 0.f) && (py < (float)H_);
    const bool mask = valid && inb;
    const float sx = fmaxf(s5 * scale_x, 1.f);
    const float sy = fmaxf(s6 * scale_y, 1.f);
    if (j == 0) {
        float4* o = (float4*)(pp + (size_t)i * 8);
        o[0] = make_float4(px, py, 1.f / sx, 1.f / sy);
        o[1] = make_float4(wv, 0.5f * (sx + sy), 0.f, 0.f);
    }
    if (!mask) return;
    const float rx = 3.f * sx, ry = 3.f * sy;
    const int ymin = max(0, (int)floorf(py - ry));
    const int ymax = min(H_ - 1, (int)ceilf(py + ry));
    const int bmin = ymin >> 1, bmax = ymax >> 1;
    const int band = bmin + j;
    if (band > bmax) return;
    const int tmin = max(0, (int)floorf((px - rx - (float)(TW - 1)) * (1.f / TW)));
    const int tmax = min(NTX - 1, (int)ceilf((px + rx) * (1.f / TW)));
    const int b = i / N_, n = i - b * N_;
    for (int t = tmin; t <= tmax; ++t) {
        const int tile = (b * NYB + band) * NTX + t;
        const int slot = atomicAdd(&counts[tile], 1);
        if (slot < CAP) lists[(size_t)tile * CAP + slot] = (ushort_t)n;
    }
}

__global__ __launch_bounds__(256)
void splat_kernel(const float* __restrict__ pp, const ushort_t* __restrict__ lists,
                  const int* __restrict__ counts, const ushort_t* __restrict__ ftb,
                  float* __restrict__ out)
{
    __shared__ __align__(16) ushort_t feats_t[2][256 * FS];
    __shared__ __align__(16) ushort_t gw_t[2][32 * FS];

    const int tid = threadIdx.x;
    const int qb = blockIdx.x;
    const int b  = qb & 1;
    const int t_ = qb >> 1;
    const int yr = t_ / NTX, xr = t_ % NTX;
    const int yh = (yr + 1) >> 1;
    const int yb = (yr & 1) ? (16 - yh) : (16 + yh);
    const int xh = (xr + 1) >> 1;
    const int txi = (xr & 1) ? (5 - xh) : (5 + xh);
    const int bid = (b * NYB + yb) * NTX + txi;
    const int y0 = yb * 2, x0 = txi * TW;

    const int cnt = min(counts[bid], CAP);
    const ushort_t* mylist = lists + (size_t)bid * CAP;
    const int gs   = tid >> 5;
    const int px32 = tid & 31;
    const float fy = (float)(y0 + (px32 >> 4));
    const float fx = (float)(x0 + (px32 & 15));
    const int chg = tid >> 4;
    const int qp  = tid & 15;
    const int bN = b * N_;
    const int lane = tid & 63;
    const int wv_  = tid >> 6;
    const int quad = lane >> 4;
    const int ln15 = lane & 15;

    f32x4 acc[2][4];
#pragma unroll
    for (int mt = 0; mt < 2; ++mt)
#pragma unroll
        for (int nt = 0; nt < 4; ++nt) acc[mt][nt] = (f32x4){0.f, 0.f, 0.f, 0.f};
    float densp = 0.f, uncp = 0.f;

    uint4 ra0, ra1, rb0, rb1;
    const int nchunks = (cnt + 31) >> 5;

    if (cnt > 0) {
        const float4* pv = (const float4*)pp;
        {
            const int n0 = mylist[min(2 * qp, cnt - 1)];
            const int n1 = mylist[min(2 * qp + 1, cnt - 1)];
            const uint4* f0 = (const uint4*)(ftb + ((size_t)(bN + n0) << 8) + chg * 16);
            const uint4* f1 = (const uint4*)(ftb + ((size_t)(bN + n1) << 8) + chg * 16);
            ra0 = f0[0]; ra1 = f0[1];
            rb0 = f1[0]; rb1 = f1[1];
        }
        for (int c = 0; c < nchunks; ++c) {
            const int buf = c & 1;
#pragma unroll
            for (int jj = 0; jj < 4; ++jj) {
                const int q = 8 * jj + gs;
                const int qi = c * 32 + q;
                const int n = mylist[min(qi, cnt - 1)];
                const float4 e0 = pv[(size_t)(bN + n) * 2 + 0];
                const float4 e1 = pv[(size_t)(bN + n) * 2 + 1];
                const float dyn = (fy - e0.y) * e0.w;
                const float dxn = (fx - e0.x) * e0.z;
                const float dist = dyn * dyn + dxn * dxn;
                float gv = 0.f;
                if (dist < 9.f) gv = __expf(-0.5f * dist) * e1.x;
                if (qi >= cnt) gv = 0.f;
                gw_t[buf][px32 * FS + q] = (ushort_t)f2bf(gv);
                densp += gv;
                uncp  += gv * e1.y;
            }
            {
                uint* dst = (uint*)&feats_t[buf][0];
#pragma unroll
                for (int jj = 0; jj < 4; ++jj) {
                    const uint u0 = (&ra0.x)[jj], v0 = (&rb0.x)[jj];
                    const int ch = chg * 16 + 2 * jj;
                    dst[ch * (FS / 2) + qp]       = (u0 & 0xffffu) | (v0 << 16);
                    dst[(ch + 1) * (FS / 2) + qp] = (u0 >> 16) | (v0 & 0xffff0000u);
                }
#pragma unroll
                for (int jj = 0; jj < 4; ++jj) {
                    const uint u0 = (&ra1.x)[jj], v0 = (&rb1.x)[jj];
                    const int ch = chg * 16 + 8 + 2 * jj;
                    dst[ch * (FS / 2) + qp]       = (u0 & 0xffffu) | (v0 << 16);
                    dst[(ch + 1) * (FS / 2) + qp] = (u0 >> 16) | (v0 & 0xffff0000u);
                }
            }
            __syncthreads();
            if (c + 1 < nchunks) {
                const int q0 = (c + 1) * 32 + 2 * qp;
                const int n0 = mylist[min(q0, cnt - 1)];
                const int n1 = mylist[min(q0 + 1, cnt - 1)];
                const uint4* f0 = (const uint4*)(ftb + ((size_t)(bN + n0) << 8) + chg * 16);
                const uint4* f1 = (const uint4*)(ftb + ((size_t)(bN + n1) << 8) + chg * 16);
                ra0 = f0[0]; ra1 = f0[1];
                rb0 = f1[0]; rb1 = f1[1];
            }
            bf16x8 af[2];
#pragma unroll
            for (int mt = 0; mt < 2; ++mt)
                af[mt] = *(const bf16x8*)&gw_t[buf][(mt * 16 + ln15) * FS + quad * 8];
#pragma unroll
            for (int nt = 0; nt < 4; ++nt) {
                const int ch0 = wv_ * 64 + nt * 16;
                const bf16x8 bf = *(const bf16x8*)&feats_t[buf][(ch0 + ln15) * FS + quad * 8];
                acc[0][nt] = __builtin_amdgcn_mfma_f32_16x16x32_bf16(af[0], bf, acc[0][nt], 0, 0, 0);
                acc[1][nt] = __builtin_amdgcn_mfma_f32_16x16x32_bf16(af[1], bf, acc[1][nt], 0, 0, 0);
            }
        }
    }

    __syncthreads();
    float* red_d = (float*)&feats_t[0][0];
    float* red_u = red_d + 8 * 36;
    red_d[gs * 36 + px32] = densp;
    red_u[gs * 36 + px32] = uncp;
    __syncthreads();
    for (int s = 4; s > 0; s >>= 1) {
        if (gs < s) {
            red_d[gs * 36 + px32] += red_d[(gs + s) * 36 + px32];
            red_u[gs * 36 + px32] += red_u[(gs + s) * 36 + px32];
        }
        __syncthreads();
    }

    if (tid < 32) {
        const int yy = y0 + (tid >> 4), xx = x0 + (tid & 15);
        const size_t pix = ((size_t)b * H_ + yy) * W_ + xx;
        float* unc_o = out + (size_t)B_ * C_ * H_ * W_;
        float* den_o = unc_o + (size_t)B_ * H_ * W_;
        const float d = fmaxf(red_d[tid], 1e-6f);
        unc_o[pix] = red_u[tid] / d;
        den_o[pix] = d;
    }

#pragma unroll
    for (int mt = 0; mt < 2; ++mt) {
        const int pxb = mt * 16 + quad * 4;
        float rinv[4];
#pragma unroll
        for (int r = 0; r < 4; ++r)
            rinv[r] = 1.f / fmaxf(red_d[pxb + r], 1e-6f);
        const int yy = y0 + mt;
#pragma unroll
        for (int nt = 0; nt < 4; ++nt) {
            const int ch = wv_ * 64 + nt * 16 + ln15;
            float4 v;
            v.x = acc[mt][nt][0] * rinv[0];
            v.y = acc[mt][nt][1] * rinv[1];
            v.z = acc[mt][nt][2] * rinv[2];
            v.w = acc[mt][nt][3] * rinv[3];
            *(float4*)(out + (((size_t)b * C_ + ch) * H_ + yy) * W_
                       + x0 + quad * 4) = v;
        }
    }
}

// ---------------------------------------------------------------------------
extern "C" void kernel_launch(void* const* d_in, const int* in_sizes, int n_in,
                              void* d_out, int out_size, void* d_ws, size_t ws_size,
                              hipStream_t stream)
{
    const float* g    = (const float*)d_in[0];
    const float* intr = (const float*)d_in[1];
    const float* w1   = (const float*)d_in[2];
    const float* b1   = (const float*)d_in[3];
    const float* w2   = (const float*)d_in[4];
    const float* b2   = (const float*)d_in[5];
    const float* w3   = (const float*)d_in[6];
    const float* b3   = (const float*)d_in[7];
    const float* fw1  = (const float*)d_in[8];
    const float* fb1  = (const float*)d_in[9];
    const float* fw2  = (const float*)d_in[10];
    const float* fb2  = (const float*)d_in[11];

    char* base = (char*)d_ws;
    const int rows = B_ * N_;                                // 4096
    ushort_t* ftb = (ushort_t*)base;                         // 2 MB bf16 [row][ch]
    float* pp     = (float*)(base + (size_t)rows * C_ * 2);  // 128 KB
    int*   counts = (int*)(pp + (size_t)8 * rows);           // 704 ints
    ushort_t* lists = (ushort_t*)(counts + NTILES2);         // 1.4 MB
    short* wt3    = (short*)(lists + (size_t)NTILES2 * CAP);
    short* wt4    = wt3 + 128 * 256;
    short* wt5    = wt4 + 256 * 256;
    float* outp   = (float*)d_out;

    void* args[] = {
        (void*)&g,   (void*)&intr, (void*)&w1,  (void*)&b1,
        (void*)&w2,  (void*)&b2,   (void*)&w3,  (void*)&b3,
        (void*)&fw1, (void*)&fb1,  (void*)&fw2, (void*)&fb2,
        (void*)&ftb, (void*)&pp,   (void*)&counts, (void*)&lists,
        (void*)&wt3, (void*)&wt4,  (void*)&wt5, (void*)&outp
    };
    hipError_t err = hipLaunchCooperativeKernel((const void*)fused_kernel,
                                                dim3(NTILES2), dim3(256),
                                                args, 0, stream);
    if (err != hipSuccess) {
        (void)hipGetLastError();   // clear sticky error, use proven path
        prep_kernel<<<dim3(256), dim3(256), 0, stream>>>(w3, fw1, fw2, wt3, wt4, wt5, counts);
        pb_mlp_kernel<<<dim3(512), dim3(512), 0, stream>>>(
            g, intr, w1, b1, w2, b2, wt3, b3, wt4, fb1, wt5, fb2, ftb, pp, counts, lists);
        splat_kernel<<<dim3(NTILES2), dim3(256), 0, stream>>>(pp, lists, counts, ftb, (float*)d_out);
    }
}

// Round 2
// 142.732 us; speedup vs baseline: 2.2130x; 2.2130x over previous
//
#include <hip/hip_runtime.h>
#include <cstdint>
#include <cstddef>

#define B_ 2
#define N_ 2048
#define C_ 256
#define H_ 64
#define W_ 176
#define TW 16
#define NTX 11                    // 176/16 tiles per row
#define NYB 32                    // 2-row bands
#define NTILES2 (B_*NYB*NTX)      // 704 tiles (16px x 2row)
#define CAP 1024                  // per-tile list cap
#define SA 260                    // mlp act LDS stride (floats)
#define FS 40                     // feats_t / gw_t row stride (ushort) = 80 B
#define CSTRIDE 16                // counts padded to 1 per 64B line (atomic contention fix)

typedef unsigned short ushort_t;
typedef short bf16x8 __attribute__((ext_vector_type(8)));
typedef float f32x4  __attribute__((ext_vector_type(4)));

__device__ __forceinline__ short f2bf(float f)   // RNE fp32->bf16
{
    unsigned u = __float_as_uint(f);
    return (short)((u + 0x7FFFu + ((u >> 16) & 1u)) >> 16);
}

// ---------------------------------------------------------------------------
// prep: zero tile counters + fp32->bf16 transposed weight convert (coalesced
// writes). grid 256 x 256.
// ---------------------------------------------------------------------------
__global__ __launch_bounds__(256)
void prep_kernel(const float* __restrict__ w3f, const float* __restrict__ fw1f,
                 const float* __restrict__ fw2f,
                 short* __restrict__ wt3, short* __restrict__ wt4,
                 short* __restrict__ wt5, int* __restrict__ counts)
{
    const int gid = blockIdx.x * 256 + threadIdx.x;
    if (gid < NTILES2 * CSTRIDE) counts[gid] = 0;
    for (int e = gid; e < 163840; e += 65536) {
        if (e < 32768) {
            const int i = e;
            wt3[i] = f2bf(w3f[(i & 127) * 256 + (i >> 7)]);
        } else if (e < 98304) {
            const int i = e - 32768;
            wt4[i] = f2bf(fw1f[(i & 255) * 256 + (i >> 8)]);
        } else {
            const int i = e - 98304;
            wt5[i] = f2bf(fw2f[(i & 255) * 256 + (i >> 8)]);
        }
    }
}

// ---------------------------------------------------------------------------
// MFMA accumulate, 8-wave MLP version.
// ---------------------------------------------------------------------------
template<int K>
__device__ __forceinline__ void mfma_acc(const short* __restrict__ wt,
                                         const float* actIn, f32x4 (&acc)[2],
                                         int wv_, int quad, int ln15)
{
#pragma unroll
    for (int ks = 0; ks < K / 32; ++ks) {
        const int kb = ks * 32 + quad * 8;
        const float4 a0 = *(const float4*)&actIn[ln15 * SA + kb];
        const float4 a1 = *(const float4*)&actIn[ln15 * SA + kb + 4];
        bf16x8 af = { f2bf(a0.x), f2bf(a0.y), f2bf(a0.z), f2bf(a0.w),
                      f2bf(a1.x), f2bf(a1.y), f2bf(a1.z), f2bf(a1.w) };
#pragma unroll
        for (int tt = 0; tt < 2; ++tt) {
            const int n0 = (wv_ * 2 + tt) * 16;
            const bf16x8 bf = *(const bf16x8*)&wt[(size_t)(n0 + ln15) * K + kb];
            acc[tt] = __builtin_amdgcn_mfma_f32_16x16x32_bf16(af, bf, acc[tt], 0, 0, 0);
        }
    }
}

// ---------------------------------------------------------------------------
// Fused MLP + param/bin, 512 threads.
// ---------------------------------------------------------------------------
__global__ __launch_bounds__(512)
void pb_mlp_kernel(const float* __restrict__ g, const float* __restrict__ intr,
                   const float* __restrict__ w1, const float* __restrict__ b1,
                   const float* __restrict__ w2, const float* __restrict__ b2,
                   const short* __restrict__ wt3, const float* __restrict__ b3,
                   const short* __restrict__ wt4, const float* __restrict__ fb1,
                   const short* __restrict__ wt5, const float* __restrict__ fb2,
                   ushort_t* __restrict__ ftb,
                   float* __restrict__ pp, int* __restrict__ counts,
                   ushort_t* __restrict__ lists)
{
    __shared__ __align__(16) float A_[16 * SA];
    __shared__ __align__(16) float Bb[16 * SA];
    const int tid = threadIdx.x;

    if (blockIdx.x < 256) {
        const int row0 = blockIdx.x * 16;
        const int lane = tid & 63;
        const int wv_  = tid >> 6;
        const int quad = lane >> 4;
        const int ln15 = lane & 15;

        if (tid < 224) {
            const int k = tid / 16, m = tid % 16;
            A_[m * SA + k] = g[(size_t)(row0 + m) * 14 + k];
        }
        __syncthreads();

        {   // L1: 14 -> 64, relu
            const int col = tid & 63;
            const int m0  = (tid >> 6) * 2;
            float acc[2];
            const float bv = b1[col];
            acc[0] = bv; acc[1] = bv;
#pragma unroll
            for (int k = 0; k < 14; ++k) {
                const float wv = w1[k * 64 + col];
                acc[0] = fmaf(A_[(m0 + 0) * SA + k], wv, acc[0]);
                acc[1] = fmaf(A_[(m0 + 1) * SA + k], wv, acc[1]);
            }
            Bb[(m0 + 0) * SA + col] = fmaxf(acc[0], 0.f);
            Bb[(m0 + 1) * SA + col] = fmaxf(acc[1], 0.f);
        }
        __syncthreads();

        {   // L2: 64 -> 128, relu
            const int col = tid & 127;
            const int m0  = (tid >> 7) * 4;
            float acc[4];
            const float bv = b2[col];
#pragma unroll
            for (int r = 0; r < 4; ++r) acc[r] = bv;
#pragma unroll 4
            for (int kq = 0; kq < 16; ++kq) {
                float wv[4];
#pragma unroll
                for (int jj = 0; jj < 4; ++jj) wv[jj] = w2[(4 * kq + jj) * 128 + col];
#pragma unroll
                for (int r = 0; r < 4; ++r) {
                    const float4 a4 = *(const float4*)&Bb[(m0 + r) * SA + 4 * kq];
                    acc[r] = fmaf(a4.x, wv[0], acc[r]);
                    acc[r] = fmaf(a4.y, wv[1], acc[r]);
                    acc[r] = fmaf(a4.z, wv[2], acc[r]);
                    acc[r] = fmaf(a4.w, wv[3], acc[r]);
                }
            }
#pragma unroll
            for (int r = 0; r < 4; ++r)
                A_[(m0 + r) * SA + col] = fmaxf(acc[r], 0.f);
        }
        __syncthreads();

        {   // L3: 128 -> 256 MFMA
            f32x4 acc[2] = {{0,0,0,0},{0,0,0,0}};
            mfma_acc<128>(wt3, A_, acc, wv_, quad, ln15);
            __syncthreads();
#pragma unroll
            for (int tt = 0; tt < 2; ++tt) {
                const int n = (wv_ * 2 + tt) * 16 + ln15;
                const float bv = b3[n];
#pragma unroll
                for (int r = 0; r < 4; ++r)
                    Bb[(quad * 4 + r) * SA + n] = acc[tt][r] + bv;
            }
        }
        __syncthreads();

        {   // L4: 256 -> 256 MFMA, relu
            f32x4 acc[2] = {{0,0,0,0},{0,0,0,0}};
            mfma_acc<256>(wt4, Bb, acc, wv_, quad, ln15);
            __syncthreads();
#pragma unroll
            for (int tt = 0; tt < 2; ++tt) {
                const int n = (wv_ * 2 + tt) * 16 + ln15;
                const float bv = fb1[n];
#pragma unroll
                for (int r = 0; r < 4; ++r)
                    A_[(quad * 4 + r) * SA + n] = fmaxf(acc[tt][r] + bv, 0.f);
            }
        }
        __syncthreads();

        {   // L5: 256 -> 256 MFMA -> global bf16
            f32x4 acc[2] = {{0,0,0,0},{0,0,0,0}};
            mfma_acc<256>(wt5, A_, acc, wv_, quad, ln15);
#pragma unroll
            for (int tt = 0; tt < 2; ++tt) {
                const int n = (wv_ * 2 + tt) * 16 + ln15;
                const float bv = fb2[n];
#pragma unroll
                for (int r = 0; r < 4; ++r)
                    ftb[(size_t)(row0 + quad * 4 + r) * 256 + n] =
                        (ushort_t)f2bf(acc[tt][r] + bv);
            }
        }
        return;
    }

    // ================= param + bin role (2-row bands) =================
    const int i = (blockIdx.x - 256) * 16 + (tid >> 5);
    const int j = tid & 31;
    const float* gi = g + (size_t)i * 14;
    const float x = gi[0], y = gi[1], z = gi[2];
    const float s5 = gi[5], s6 = gi[6], wv = gi[12];
    const float k00 = intr[0], k01 = intr[1], k02 = intr[2];
    const float k10 = intr[3], k11 = intr[4], k12 = intr[5];
    const float k20 = intr[6], k21 = intr[7], k22 = intr[8];
    const float projx = k00 * x + k01 * y + k02 * z;
    const float projy = k10 * x + k11 * y + k12 * z;
    const float projz = k20 * x + k21 * y + k22 * z;
    const float inv = 1.f / (projz + 1e-6f);
    const float scale_x = (float)W_ / k02 * 0.5f;
    const float scale_y = (float)H_ / k12 * 0.5f;
    const float px = projx * inv * scale_x;
    const float py = projy * inv * scale_y;
    const bool valid = z > 0.1f;
    const bool inb = (px >= 0.f) && (px < (float)W_) && (py >= 0.f) && (py < (float)H_);
    const bool mask = valid && inb;
    const float sx = fmaxf(s5 * scale_x, 1.f);
    const float sy = fmaxf(s6 * scale_y, 1.f);
    if (j == 0) {
        float4* o = (float4*)(pp + (size_t)i * 8);
        o[0] = make_float4(px, py, 1.f / sx, 1.f / sy);
        o[1] = make_float4(wv, 0.5f * (sx + sy), 0.f, 0.f);
    }
    if (!mask) return;
    const float rx = 3.f * sx, ry = 3.f * sy;
    const int ymin = max(0, (int)floorf(py - ry));
    const int ymax = min(H_ - 1, (int)ceilf(py + ry));
    const int bmin = ymin >> 1, bmax = ymax >> 1;
    const int band = bmin + j;
    if (band > bmax) return;
    const int tmin = max(0, (int)floorf((px - rx - (float)(TW - 1)) * (1.f / TW)));
    const int tmax = min(NTX - 1, (int)ceilf((px + rx) * (1.f / TW)));
    const int b = i / N_, n = i - b * N_;
    for (int t = tmin; t <= tmax; ++t) {
        const int tile = (b * NYB + band) * NTX + t;
        const int slot = atomicAdd(&counts[tile * CSTRIDE], 1);
        if (slot < CAP) lists[(size_t)tile * CAP + slot] = (ushort_t)n;
    }
}

// ---------------------------------------------------------------------------
// Splat with MFMA phase B. Block = 16px x 2row tile; chunks of K=32.
// ---------------------------------------------------------------------------
__global__ __launch_bounds__(256)
void splat_kernel(const float* __restrict__ pp, const ushort_t* __restrict__ lists,
                  const int* __restrict__ counts, const ushort_t* __restrict__ ftb,
                  float* __restrict__ out)
{
    __shared__ __align__(16) ushort_t feats_t[2][256 * FS];  // 2 x 20 KB
    __shared__ __align__(16) ushort_t gw_t[2][32 * FS];      // 2 x 2.5 KB

    const int tid = threadIdx.x;
    // center-first tile decode
    const int qb = blockIdx.x;
    const int b  = qb & 1;
    const int t_ = qb >> 1;
    const int yr = t_ / NTX, xr = t_ % NTX;
    const int yh = (yr + 1) >> 1;
    const int yb = (yr & 1) ? (16 - yh) : (16 + yh);
    const int xh = (xr + 1) >> 1;
    const int txi = (xr & 1) ? (5 - xh) : (5 + xh);
    const int bid = (b * NYB + yb) * NTX + txi;
    const int y0 = yb * 2, x0 = txi * TW;

    const int cnt = min(counts[bid * CSTRIDE], CAP);
    const ushort_t* mylist = lists + (size_t)bid * CAP;
    const int gs   = tid >> 5;            // phase A gaussian sub-slot (0..7)
    const int px32 = tid & 31;            // phase A pixel (row*16+x)
    const float fy = (float)(y0 + (px32 >> 4));
    const float fx = (float)(x0 + (px32 & 15));
    const int chg = tid >> 4;             // stage: ch group (0..15), 16 ch each
    const int qp  = tid & 15;             // stage: q pair (0..15)
    const int bN = b * N_;
    const int lane = tid & 63;
    const int wv_  = tid >> 6;
    const int quad = lane >> 4;
    const int ln15 = lane & 15;

    f32x4 acc[2][4];
#pragma unroll
    for (int mt = 0; mt < 2; ++mt)
#pragma unroll
        for (int nt = 0; nt < 4; ++nt) acc[mt][nt] = (f32x4){0.f, 0.f, 0.f, 0.f};
    float densp = 0.f, uncp = 0.f;

    uint4 ra0, ra1, rb0, rb1;             // staged 16ch x 2 rows
    const int nchunks = (cnt + 31) >> 5;

    if (cnt > 0) {
        const float4* pv = (const float4*)pp;
        {   // prefetch chunk 0 rows
            const int n0 = mylist[min(2 * qp, cnt - 1)];
            const int n1 = mylist[min(2 * qp + 1, cnt - 1)];
            const uint4* f0 = (const uint4*)(ftb + ((size_t)(bN + n0) << 8) + chg * 16);
            const uint4* f1 = (const uint4*)(ftb + ((size_t)(bN + n1) << 8) + chg * 16);
            ra0 = f0[0]; ra1 = f0[1];
            rb0 = f1[0]; rb1 = f1[1];
        }
        for (int c = 0; c < nchunks; ++c) {
            const int buf = c & 1;
            // ---- phase A: 4 gw per thread -> gw_t[buf] (bf16) ----
#pragma unroll
            for (int jj = 0; jj < 4; ++jj) {
                const int q = 8 * jj + gs;
                const int qi = c * 32 + q;
                const int n = mylist[min(qi, cnt - 1)];
                const float4 e0 = pv[(size_t)(bN + n) * 2 + 0];
                const float4 e1 = pv[(size_t)(bN + n) * 2 + 1];
                const float dyn = (fy - e0.y) * e0.w;
                const float dxn = (fx - e0.x) * e0.z;
                const float dist = dyn * dyn + dxn * dxn;
                float gv = 0.f;
                if (dist < 9.f) gv = __expf(-0.5f * dist) * e1.x;
                if (qi >= cnt) gv = 0.f;
                gw_t[buf][px32 * FS + q] = (ushort_t)f2bf(gv);
                densp += gv;
                uncp  += gv * e1.y;
            }
            // ---- stage: transpose regs -> feats_t[buf][ch][k] ----
            {
                uint* dst = (uint*)&feats_t[buf][0];
#pragma unroll
                for (int jj = 0; jj < 4; ++jj) {
                    const uint u0 = (&ra0.x)[jj], v0 = (&rb0.x)[jj];
                    const int ch = chg * 16 + 2 * jj;
                    dst[ch * (FS / 2) + qp]       = (u0 & 0xffffu) | (v0 << 16);
                    dst[(ch + 1) * (FS / 2) + qp] = (u0 >> 16) | (v0 & 0xffff0000u);
                }
#pragma unroll
                for (int jj = 0; jj < 4; ++jj) {
                    const uint u0 = (&ra1.x)[jj], v0 = (&rb1.x)[jj];
                    const int ch = chg * 16 + 8 + 2 * jj;
                    dst[ch * (FS / 2) + qp]       = (u0 & 0xffffu) | (v0 << 16);
                    dst[(ch + 1) * (FS / 2) + qp] = (u0 >> 16) | (v0 & 0xffff0000u);
                }
            }
            __syncthreads();
            // ---- prefetch chunk c+1 rows (overlaps phase B) ----
            if (c + 1 < nchunks) {
                const int q0 = (c + 1) * 32 + 2 * qp;
                const int n0 = mylist[min(q0, cnt - 1)];
                const int n1 = mylist[min(q0 + 1, cnt - 1)];
                const uint4* f0 = (const uint4*)(ftb + ((size_t)(bN + n0) << 8) + chg * 16);
                const uint4* f1 = (const uint4*)(ftb + ((size_t)(bN + n1) << 8) + chg * 16);
                ra0 = f0[0]; ra1 = f0[1];
                rb0 = f1[0]; rb1 = f1[1];
            }
            // ---- phase B: 8 MFMA per wave ----
            bf16x8 af[2];
#pragma unroll
            for (int mt = 0; mt < 2; ++mt)
                af[mt] = *(const bf16x8*)&gw_t[buf][(mt * 16 + ln15) * FS + quad * 8];
#pragma unroll
            for (int nt = 0; nt < 4; ++nt) {
                const int ch0 = wv_ * 64 + nt * 16;
                const bf16x8 bf = *(const bf16x8*)&feats_t[buf][(ch0 + ln15) * FS + quad * 8];
                acc[0][nt] = __builtin_amdgcn_mfma_f32_16x16x32_bf16(af[0], bf, acc[0][nt], 0, 0, 0);
                acc[1][nt] = __builtin_amdgcn_mfma_f32_16x16x32_bf16(af[1], bf, acc[1][nt], 0, 0, 0);
            }
        }
    }

    // ---- density / uncertainty reduction over 8 gs-groups ----
    __syncthreads();
    float* red_d = (float*)&feats_t[0][0];   // 8 x 36
    float* red_u = red_d + 8 * 36;
    red_d[gs * 36 + px32] = densp;
    red_u[gs * 36 + px32] = uncp;
    __syncthreads();
    for (int s = 4; s > 0; s >>= 1) {
        if (gs < s) {
            red_d[gs * 36 + px32] += red_d[(gs + s) * 36 + px32];
            red_u[gs * 36 + px32] += red_u[(gs + s) * 36 + px32];
        }
        __syncthreads();
    }

    if (tid < 32) {
        const int yy = y0 + (tid >> 4), xx = x0 + (tid & 15);
        const size_t pix = ((size_t)b * H_ + yy) * W_ + xx;
        float* unc_o = out + (size_t)B_ * C_ * H_ * W_;
        float* den_o = unc_o + (size_t)B_ * H_ * W_;
        const float d = fmaxf(red_d[tid], 1e-6f);
        unc_o[pix] = red_u[tid] / d;
        den_o[pix] = d;
    }

    // ---- feature stores: lane = ch (ln15), 4 consecutive x per acc ----
#pragma unroll
    for (int mt = 0; mt < 2; ++mt) {
        const int pxb = mt * 16 + quad * 4;
        float rinv[4];
#pragma unroll
        for (int r = 0; r < 4; ++r)
            rinv[r] = 1.f / fmaxf(red_d[pxb + r], 1e-6f);
        const int yy = y0 + mt;
#pragma unroll
        for (int nt = 0; nt < 4; ++nt) {
            const int ch = wv_ * 64 + nt * 16 + ln15;
            float4 v;
            v.x = acc[mt][nt][0] * rinv[0];
            v.y = acc[mt][nt][1] * rinv[1];
            v.z = acc[mt][nt][2] * rinv[2];
            v.w = acc[mt][nt][3] * rinv[3];
            *(float4*)(out + (((size_t)b * C_ + ch) * H_ + yy) * W_
                       + x0 + quad * 4) = v;
        }
    }
}

// ---------------------------------------------------------------------------
extern "C" void kernel_launch(void* const* d_in, const int* in_sizes, int n_in,
                              void* d_out, int out_size, void* d_ws, size_t ws_size,
                              hipStream_t stream)
{
    const float* g    = (const float*)d_in[0];
    const float* intr = (const float*)d_in[1];
    const float* w1   = (const float*)d_in[2];
    const float* b1   = (const float*)d_in[3];
    const float* w2   = (const float*)d_in[4];
    const float* b2   = (const float*)d_in[5];
    const float* w3   = (const float*)d_in[6];
    const float* b3   = (const float*)d_in[7];
    const float* fw1  = (const float*)d_in[8];
    const float* fb1  = (const float*)d_in[9];
    const float* fw2  = (const float*)d_in[10];
    const float* fb2  = (const float*)d_in[11];

    char* base = (char*)d_ws;
    const int rows = B_ * N_;                                // 4096
    ushort_t* ftb = (ushort_t*)base;                         // 2 MB bf16 [row][ch]
    float* pp     = (float*)(base + (size_t)rows * C_ * 2);  // 128 KB
    int*   counts = (int*)(pp + (size_t)8 * rows);           // 704 x 16 ints (64B/line)
    ushort_t* lists = (ushort_t*)(counts + NTILES2 * CSTRIDE); // 1.4 MB
    short* wt3    = (short*)(lists + (size_t)NTILES2 * CAP);
    short* wt4    = wt3 + 128 * 256;
    short* wt5    = wt4 + 256 * 256;

    prep_kernel<<<dim3(256), dim3(256), 0, stream>>>(w3, fw1, fw2, wt3, wt4, wt5, counts);
    pb_mlp_kernel<<<dim3(512), dim3(512), 0, stream>>>(
        g, intr, w1, b1, w2, b2, wt3, b3, wt4, fb1, wt5, fb2, ftb, pp, counts, lists);
    splat_kernel<<<dim3(NTILES2), dim3(256), 0, stream>>>(pp, lists, counts, ftb, (float*)d_out);
}

// Round 3
// 139.717 us; speedup vs baseline: 2.2608x; 1.0216x over previous
//
#include <hip/hip_runtime.h>
#include <cstdint>
#include <cstddef>

#define B_ 2
#define N_ 2048
#define C_ 256
#define H_ 64
#define W_ 176
#define TW 16
#define NTX 11                    // 176/16 tiles per row
#define NYB 32                    // 2-row bands
#define NTILES2 (B_*NYB*NTX)      // 704 tiles (16px x 2row)
#define CAP 1024                  // per-tile list cap
#define SA 260                    // mlp act LDS stride (floats)
#define FS 40                     // feats_t / gw_t row stride (ushort) = 80 B
#define CSTRIDE 16                // counts padded to 1 per 64B line (atomic contention fix)

typedef unsigned short ushort_t;
typedef short bf16x8 __attribute__((ext_vector_type(8)));
typedef float f32x4  __attribute__((ext_vector_type(4)));

__device__ __forceinline__ short f2bf(float f)   // RNE fp32->bf16
{
    unsigned u = __float_as_uint(f);
    return (short)((u + 0x7FFFu + ((u >> 16) & 1u)) >> 16);
}

// ---------------------------------------------------------------------------
// prep: zero tile counters + fp32->bf16 transposed weight convert.
// COALESCED reads (stride-1 over source), scattered 2B stores (posted, no
// stall). grid 256 x 256.
// ---------------------------------------------------------------------------
__global__ __launch_bounds__(256)
void prep_kernel(const float* __restrict__ w3f, const float* __restrict__ fw1f,
                 const float* __restrict__ fw2f,
                 short* __restrict__ wt3, short* __restrict__ wt4,
                 short* __restrict__ wt5, int* __restrict__ counts)
{
    const int gid = blockIdx.x * 256 + threadIdx.x;
    if (gid < NTILES2 * CSTRIDE) counts[gid] = 0;
    for (int e = gid; e < 163840; e += 65536) {
        if (e < 32768) {                      // w3f[k][n] (128x256) -> wt3[n*128+k]
            const int k = e >> 8, n = e & 255;
            wt3[n * 128 + k] = f2bf(w3f[e]);
        } else if (e < 98304) {               // fw1f[k][n] (256x256) -> wt4[n*256+k]
            const int e2 = e - 32768;
            const int k = e2 >> 8, n = e2 & 255;
            wt4[n * 256 + k] = f2bf(fw1f[e2]);
        } else {                              // fw2f[k][n] (256x256) -> wt5[n*256+k]
            const int e2 = e - 98304;
            const int k = e2 >> 8, n = e2 & 255;
            wt5[n * 256 + k] = f2bf(fw2f[e2]);
        }
    }
}

// ---------------------------------------------------------------------------
// MFMA accumulate, 8-wave MLP version, with FULL-LAYER weight preload.
// All K/16 bf16x8 global loads issued up front (static-indexed register
// array) so L2 latency overlaps the f2bf conversion + MFMA chain.
// ---------------------------------------------------------------------------
template<int K>
__device__ __forceinline__ void mfma_acc(const short* __restrict__ wt,
                                         const float* actIn, f32x4 (&acc)[2],
                                         int wv_, int quad, int ln15)
{
    bf16x8 wreg[K / 16];                      // K=256: 16 x 4 VGPR = 64 VGPR
#pragma unroll
    for (int ks = 0; ks < K / 32; ++ks) {
        const int kb = ks * 32 + quad * 8;
#pragma unroll
        for (int tt = 0; tt < 2; ++tt) {
            const int n0 = (wv_ * 2 + tt) * 16;
            wreg[ks * 2 + tt] = *(const bf16x8*)&wt[(size_t)(n0 + ln15) * K + kb];
        }
    }
#pragma unroll
    for (int ks = 0; ks < K / 32; ++ks) {
        const int kb = ks * 32 + quad * 8;
        const float4 a0 = *(const float4*)&actIn[ln15 * SA + kb];
        const float4 a1 = *(const float4*)&actIn[ln15 * SA + kb + 4];
        bf16x8 af = { f2bf(a0.x), f2bf(a0.y), f2bf(a0.z), f2bf(a0.w),
                      f2bf(a1.x), f2bf(a1.y), f2bf(a1.z), f2bf(a1.w) };
#pragma unroll
        for (int tt = 0; tt < 2; ++tt)
            acc[tt] = __builtin_amdgcn_mfma_f32_16x16x32_bf16(af, wreg[ks * 2 + tt],
                                                              acc[tt], 0, 0, 0);
    }
}

// ---------------------------------------------------------------------------
// Fused MLP + param/bin, 512 threads. launch_bounds(512,4): 128-VGPR cap,
// keeps 2 blocks/CU while allowing the 64-VGPR weight preload.
// ---------------------------------------------------------------------------
__global__ __launch_bounds__(512, 4)
void pb_mlp_kernel(const float* __restrict__ g, const float* __restrict__ intr,
                   const float* __restrict__ w1, const float* __restrict__ b1,
                   const float* __restrict__ w2, const float* __restrict__ b2,
                   const short* __restrict__ wt3, const float* __restrict__ b3,
                   const short* __restrict__ wt4, const float* __restrict__ fb1,
                   const short* __restrict__ wt5, const float* __restrict__ fb2,
                   ushort_t* __restrict__ ftb,
                   float* __restrict__ pp, int* __restrict__ counts,
                   ushort_t* __restrict__ lists)
{
    __shared__ __align__(16) float A_[16 * SA];
    __shared__ __align__(16) float Bb[16 * SA];
    const int tid = threadIdx.x;

    if (blockIdx.x < 256) {
        const int row0 = blockIdx.x * 16;
        const int lane = tid & 63;
        const int wv_  = tid >> 6;
        const int quad = lane >> 4;
        const int ln15 = lane & 15;

        if (tid < 224) {
            const int k = tid / 16, m = tid % 16;
            A_[m * SA + k] = g[(size_t)(row0 + m) * 14 + k];
        }
        __syncthreads();

        {   // L1: 14 -> 64, relu
            const int col = tid & 63;
            const int m0  = (tid >> 6) * 2;
            float acc[2];
            const float bv = b1[col];
            acc[0] = bv; acc[1] = bv;
#pragma unroll
            for (int k = 0; k < 14; ++k) {
                const float wv = w1[k * 64 + col];
                acc[0] = fmaf(A_[(m0 + 0) * SA + k], wv, acc[0]);
                acc[1] = fmaf(A_[(m0 + 1) * SA + k], wv, acc[1]);
            }
            Bb[(m0 + 0) * SA + col] = fmaxf(acc[0], 0.f);
            Bb[(m0 + 1) * SA + col] = fmaxf(acc[1], 0.f);
        }
        __syncthreads();

        {   // L2: 64 -> 128, relu
            const int col = tid & 127;
            const int m0  = (tid >> 7) * 4;
            float acc[4];
            const float bv = b2[col];
#pragma unroll
            for (int r = 0; r < 4; ++r) acc[r] = bv;
#pragma unroll 4
            for (int kq = 0; kq < 16; ++kq) {
                float wv[4];
#pragma unroll
                for (int jj = 0; jj < 4; ++jj) wv[jj] = w2[(4 * kq + jj) * 128 + col];
#pragma unroll
                for (int r = 0; r < 4; ++r) {
                    const float4 a4 = *(const float4*)&Bb[(m0 + r) * SA + 4 * kq];
                    acc[r] = fmaf(a4.x, wv[0], acc[r]);
                    acc[r] = fmaf(a4.y, wv[1], acc[r]);
                    acc[r] = fmaf(a4.z, wv[2], acc[r]);
                    acc[r] = fmaf(a4.w, wv[3], acc[r]);
                }
            }
#pragma unroll
            for (int r = 0; r < 4; ++r)
                A_[(m0 + r) * SA + col] = fmaxf(acc[r], 0.f);
        }
        __syncthreads();

        {   // L3: 128 -> 256 MFMA
            f32x4 acc[2] = {{0,0,0,0},{0,0,0,0}};
            mfma_acc<128>(wt3, A_, acc, wv_, quad, ln15);
            __syncthreads();
#pragma unroll
            for (int tt = 0; tt < 2; ++tt) {
                const int n = (wv_ * 2 + tt) * 16 + ln15;
                const float bv = b3[n];
#pragma unroll
                for (int r = 0; r < 4; ++r)
                    Bb[(quad * 4 + r) * SA + n] = acc[tt][r] + bv;
            }
        }
        __syncthreads();

        {   // L4: 256 -> 256 MFMA, relu
            f32x4 acc[2] = {{0,0,0,0},{0,0,0,0}};
            mfma_acc<256>(wt4, Bb, acc, wv_, quad, ln15);
            __syncthreads();
#pragma unroll
            for (int tt = 0; tt < 2; ++tt) {
                const int n = (wv_ * 2 + tt) * 16 + ln15;
                const float bv = fb1[n];
#pragma unroll
                for (int r = 0; r < 4; ++r)
                    A_[(quad * 4 + r) * SA + n] = fmaxf(acc[tt][r] + bv, 0.f);
            }
        }
        __syncthreads();

        {   // L5: 256 -> 256 MFMA -> global bf16
            f32x4 acc[2] = {{0,0,0,0},{0,0,0,0}};
            mfma_acc<256>(wt5, A_, acc, wv_, quad, ln15);
#pragma unroll
            for (int tt = 0; tt < 2; ++tt) {
                const int n = (wv_ * 2 + tt) * 16 + ln15;
                const float bv = fb2[n];
#pragma unroll
                for (int r = 0; r < 4; ++r)
                    ftb[(size_t)(row0 + quad * 4 + r) * 256 + n] =
                        (ushort_t)f2bf(acc[tt][r] + bv);
            }
        }
        return;
    }

    // ================= param + bin role (2-row bands) =================
    const int i = (blockIdx.x - 256) * 16 + (tid >> 5);
    const int j = tid & 31;
    const float* gi = g + (size_t)i * 14;
    const float x = gi[0], y = gi[1], z = gi[2];
    const float s5 = gi[5], s6 = gi[6], wv = gi[12];
    const float k00 = intr[0], k01 = intr[1], k02 = intr[2];
    const float k10 = intr[3], k11 = intr[4], k12 = intr[5];
    const float k20 = intr[6], k21 = intr[7], k22 = intr[8];
    const float projx = k00 * x + k01 * y + k02 * z;
    const float projy = k10 * x + k11 * y + k12 * z;
    const float projz = k20 * x + k21 * y + k22 * z;
    const float inv = 1.f / (projz + 1e-6f);
    const float scale_x = (float)W_ / k02 * 0.5f;
    const float scale_y = (float)H_ / k12 * 0.5f;
    const float px = projx * inv * scale_x;
    const float py = projy * inv * scale_y;
    const bool valid = z > 0.1f;
    const bool inb = (px >= 0.f) && (px < (float)W_) && (py >= 0.f) && (py < (float)H_);
    const bool mask = valid && inb;
    const float sx = fmaxf(s5 * scale_x, 1.f);
    const float sy = fmaxf(s6 * scale_y, 1.f);
    if (j == 0) {
        float4* o = (float4*)(pp + (size_t)i * 8);
        o[0] = make_float4(px, py, 1.f / sx, 1.f / sy);
        o[1] = make_float4(wv, 0.5f * (sx + sy), 0.f, 0.f);
    }
    if (!mask) return;
    const float rx = 3.f * sx, ry = 3.f * sy;
    const int ymin = max(0, (int)floorf(py - ry));
    const int ymax = min(H_ - 1, (int)ceilf(py + ry));
    const int bmin = ymin >> 1, bmax = ymax >> 1;
    const int band = bmin + j;
    if (band > bmax) return;
    const int tmin = max(0, (int)floorf((px - rx - (float)(TW - 1)) * (1.f / TW)));
    const int tmax = min(NTX - 1, (int)ceilf((px + rx) * (1.f / TW)));
    const int b = i / N_, n = i - b * N_;
    for (int t = tmin; t <= tmax; ++t) {
        const int tile = (b * NYB + band) * NTX + t;
        const int slot = atomicAdd(&counts[tile * CSTRIDE], 1);
        if (slot < CAP) lists[(size_t)tile * CAP + slot] = (ushort_t)n;
    }
}

// ---------------------------------------------------------------------------
// Splat with MFMA phase B. Block = 16px x 2row tile; chunks of K=32.
// ---------------------------------------------------------------------------
__global__ __launch_bounds__(256)
void splat_kernel(const float* __restrict__ pp, const ushort_t* __restrict__ lists,
                  const int* __restrict__ counts, const ushort_t* __restrict__ ftb,
                  float* __restrict__ out)
{
    __shared__ __align__(16) ushort_t feats_t[2][256 * FS];  // 2 x 20 KB
    __shared__ __align__(16) ushort_t gw_t[2][32 * FS];      // 2 x 2.5 KB

    const int tid = threadIdx.x;
    // center-first tile decode
    const int qb = blockIdx.x;
    const int b  = qb & 1;
    const int t_ = qb >> 1;
    const int yr = t_ / NTX, xr = t_ % NTX;
    const int yh = (yr + 1) >> 1;
    const int yb = (yr & 1) ? (16 - yh) : (16 + yh);
    const int xh = (xr + 1) >> 1;
    const int txi = (xr & 1) ? (5 - xh) : (5 + xh);
    const int bid = (b * NYB + yb) * NTX + txi;
    const int y0 = yb * 2, x0 = txi * TW;

    const int cnt = min(counts[bid * CSTRIDE], CAP);
    const ushort_t* mylist = lists + (size_t)bid * CAP;
    const int gs   = tid >> 5;            // phase A gaussian sub-slot (0..7)
    const int px32 = tid & 31;            // phase A pixel (row*16+x)
    const float fy = (float)(y0 + (px32 >> 4));
    const float fx = (float)(x0 + (px32 & 15));
    const int chg = tid >> 4;             // stage: ch group (0..15), 16 ch each
    const int qp  = tid & 15;             // stage: q pair (0..15)
    const int bN = b * N_;
    const int lane = tid & 63;
    const int wv_  = tid >> 6;
    const int quad = lane >> 4;
    const int ln15 = lane & 15;

    f32x4 acc[2][4];
#pragma unroll
    for (int mt = 0; mt < 2; ++mt)
#pragma unroll
        for (int nt = 0; nt < 4; ++nt) acc[mt][nt] = (f32x4){0.f, 0.f, 0.f, 0.f};
    float densp = 0.f, uncp = 0.f;

    uint4 ra0, ra1, rb0, rb1;             // staged 16ch x 2 rows
    const int nchunks = (cnt + 31) >> 5;

    if (cnt > 0) {
        const float4* pv = (const float4*)pp;
        {   // prefetch chunk 0 rows
            const int n0 = mylist[min(2 * qp, cnt - 1)];
            const int n1 = mylist[min(2 * qp + 1, cnt - 1)];
            const uint4* f0 = (const uint4*)(ftb + ((size_t)(bN + n0) << 8) + chg * 16);
            const uint4* f1 = (const uint4*)(ftb + ((size_t)(bN + n1) << 8) + chg * 16);
            ra0 = f0[0]; ra1 = f0[1];
            rb0 = f1[0]; rb1 = f1[1];
        }
        for (int c = 0; c < nchunks; ++c) {
            const int buf = c & 1;
            // ---- phase A: 4 gw per thread -> gw_t[buf] (bf16) ----
#pragma unroll
            for (int jj = 0; jj < 4; ++jj) {
                const int q = 8 * jj + gs;
                const int qi = c * 32 + q;
                const int n = mylist[min(qi, cnt - 1)];
                const float4 e0 = pv[(size_t)(bN + n) * 2 + 0];
                const float4 e1 = pv[(size_t)(bN + n) * 2 + 1];
                const float dyn = (fy - e0.y) * e0.w;
                const float dxn = (fx - e0.x) * e0.z;
                const float dist = dyn * dyn + dxn * dxn;
                float gv = 0.f;
                if (dist < 9.f) gv = __expf(-0.5f * dist) * e1.x;
                if (qi >= cnt) gv = 0.f;
                gw_t[buf][px32 * FS + q] = (ushort_t)f2bf(gv);
                densp += gv;
                uncp  += gv * e1.y;
            }
            // ---- stage: transpose regs -> feats_t[buf][ch][k] ----
            {
                uint* dst = (uint*)&feats_t[buf][0];
#pragma unroll
                for (int jj = 0; jj < 4; ++jj) {
                    const uint u0 = (&ra0.x)[jj], v0 = (&rb0.x)[jj];
                    const int ch = chg * 16 + 2 * jj;
                    dst[ch * (FS / 2) + qp]       = (u0 & 0xffffu) | (v0 << 16);
                    dst[(ch + 1) * (FS / 2) + qp] = (u0 >> 16) | (v0 & 0xffff0000u);
                }
#pragma unroll
                for (int jj = 0; jj < 4; ++jj) {
                    const uint u0 = (&ra1.x)[jj], v0 = (&rb1.x)[jj];
                    const int ch = chg * 16 + 8 + 2 * jj;
                    dst[ch * (FS / 2) + qp]       = (u0 & 0xffffu) | (v0 << 16);
                    dst[(ch + 1) * (FS / 2) + qp] = (u0 >> 16) | (v0 & 0xffff0000u);
                }
            }
            __syncthreads();
            // ---- prefetch chunk c+1 rows (overlaps phase B) ----
            if (c + 1 < nchunks) {
                const int q0 = (c + 1) * 32 + 2 * qp;
                const int n0 = mylist[min(q0, cnt - 1)];
                const int n1 = mylist[min(q0 + 1, cnt - 1)];
                const uint4* f0 = (const uint4*)(ftb + ((size_t)(bN + n0) << 8) + chg * 16);
                const uint4* f1 = (const uint4*)(ftb + ((size_t)(bN + n1) << 8) + chg * 16);
                ra0 = f0[0]; ra1 = f0[1];
                rb0 = f1[0]; rb1 = f1[1];
            }
            // ---- phase B: 8 MFMA per wave ----
            bf16x8 af[2];
#pragma unroll
            for (int mt = 0; mt < 2; ++mt)
                af[mt] = *(const bf16x8*)&gw_t[buf][(mt * 16 + ln15) * FS + quad * 8];
#pragma unroll
            for (int nt = 0; nt < 4; ++nt) {
                const int ch0 = wv_ * 64 + nt * 16;
                const bf16x8 bf = *(const bf16x8*)&feats_t[buf][(ch0 + ln15) * FS + quad * 8];
                acc[0][nt] = __builtin_amdgcn_mfma_f32_16x16x32_bf16(af[0], bf, acc[0][nt], 0, 0, 0);
                acc[1][nt] = __builtin_amdgcn_mfma_f32_16x16x32_bf16(af[1], bf, acc[1][nt], 0, 0, 0);
            }
        }
    }

    // ---- density / uncertainty reduction over 8 gs-groups ----
    __syncthreads();
    float* red_d = (float*)&feats_t[0][0];   // 8 x 36
    float* red_u = red_d + 8 * 36;
    red_d[gs * 36 + px32] = densp;
    red_u[gs * 36 + px32] = uncp;
    __syncthreads();
    for (int s = 4; s > 0; s >>= 1) {
        if (gs < s) {
            red_d[gs * 36 + px32] += red_d[(gs + s) * 36 + px32];
            red_u[gs * 36 + px32] += red_u[(gs + s) * 36 + px32];
        }
        __syncthreads();
    }

    if (tid < 32) {
        const int yy = y0 + (tid >> 4), xx = x0 + (tid & 15);
        const size_t pix = ((size_t)b * H_ + yy) * W_ + xx;
        float* unc_o = out + (size_t)B_ * C_ * H_ * W_;
        float* den_o = unc_o + (size_t)B_ * H_ * W_;
        const float d = fmaxf(red_d[tid], 1e-6f);
        unc_o[pix] = red_u[tid] / d;
        den_o[pix] = d;
    }

    // ---- feature stores: lane = ch (ln15), 4 consecutive x per acc ----
#pragma unroll
    for (int mt = 0; mt < 2; ++mt) {
        const int pxb = mt * 16 + quad * 4;
        float rinv[4];
#pragma unroll
        for (int r = 0; r < 4; ++r)
            rinv[r] = 1.f / fmaxf(red_d[pxb + r], 1e-6f);
        const int yy = y0 + mt;
#pragma unroll
        for (int nt = 0; nt < 4; ++nt) {
            const int ch = wv_ * 64 + nt * 16 + ln15;
            float4 v;
            v.x = acc[mt][nt][0] * rinv[0];
            v.y = acc[mt][nt][1] * rinv[1];
            v.z = acc[mt][nt][2] * rinv[2];
            v.w = acc[mt][nt][3] * rinv[3];
            *(float4*)(out + (((size_t)b * C_ + ch) * H_ + yy) * W_
                       + x0 + quad * 4) = v;
        }
    }
}

// ---------------------------------------------------------------------------
extern "C" void kernel_launch(void* const* d_in, const int* in_sizes, int n_in,
                              void* d_out, int out_size, void* d_ws, size_t ws_size,
                              hipStream_t stream)
{
    const float* g    = (const float*)d_in[0];
    const float* intr = (const float*)d_in[1];
    const float* w1   = (const float*)d_in[2];
    const float* b1   = (const float*)d_in[3];
    const float* w2   = (const float*)d_in[4];
    const float* b2   = (const float*)d_in[5];
    const float* w3   = (const float*)d_in[6];
    const float* b3   = (const float*)d_in[7];
    const float* fw1  = (const float*)d_in[8];
    const float* fb1  = (const float*)d_in[9];
    const float* fw2  = (const float*)d_in[10];
    const float* fb2  = (const float*)d_in[11];

    char* base = (char*)d_ws;
    const int rows = B_ * N_;                                // 4096
    ushort_t* ftb = (ushort_t*)base;                         // 2 MB bf16 [row][ch]
    float* pp     = (float*)(base + (size_t)rows * C_ * 2);  // 128 KB
    int*   counts = (int*)(pp + (size_t)8 * rows);           // 704 x 16 ints (64B/line)
    ushort_t* lists = (ushort_t*)(counts + NTILES2 * CSTRIDE); // 1.4 MB
    short* wt3    = (short*)(lists + (size_t)NTILES2 * CAP);
    short* wt4    = wt3 + 128 * 256;
    short* wt5    = wt4 + 256 * 256;

    prep_kernel<<<dim3(256), dim3(256), 0, stream>>>(w3, fw1, fw2, wt3, wt4, wt5, counts);
    pb_mlp_kernel<<<dim3(512), dim3(512), 0, stream>>>(
        g, intr, w1, b1, w2, b2, wt3, b3, wt4, fb1, wt5, fb2, ftb, pp, counts, lists);
    splat_kernel<<<dim3(NTILES2), dim3(256), 0, stream>>>(pp, lists, counts, ftb, (float*)d_out);
}

// Round 4
// 133.887 us; speedup vs baseline: 2.3592x; 1.0435x over previous
//
#include <hip/hip_runtime.h>
#include <cstdint>
#include <cstddef>

#define B_ 2
#define N_ 2048
#define C_ 256
#define H_ 64
#define W_ 176
#define TW 16
#define NTX 11                    // 176/16 tiles per row
#define NYB 32                    // 2-row bands
#define NTILES2 (B_*NYB*NTX)      // 704 tiles (16px x 2row)
#define NSUB 8                    // per-tile counter/list shards (atomic contention /8)
#define SUBCAP 256                // per-shard list cap (8*256 = 2048 total/tile)
#define SA 260                    // mlp act LDS stride (floats)
#define FS 40                     // feats_t / gw_t row stride (ushort) = 80 B
#define CSTRIDE 16                // counters padded to 1 per 64B line

typedef unsigned short ushort_t;
typedef short bf16x8 __attribute__((ext_vector_type(8)));
typedef float f32x4  __attribute__((ext_vector_type(4)));

__device__ __forceinline__ short f2bf(float f)   // RNE fp32->bf16
{
    unsigned u = __float_as_uint(f);
    return (short)((u + 0x7FFFu + ((u >> 16) & 1u)) >> 16);
}

// ---------------------------------------------------------------------------
// prep: zero tile counters + fp32->bf16 transposed weight convert.
// COALESCED reads, scattered 2B stores (posted). grid 256 x 256.
// ---------------------------------------------------------------------------
__global__ __launch_bounds__(256)
void prep_kernel(const float* __restrict__ w3f, const float* __restrict__ fw1f,
                 const float* __restrict__ fw2f,
                 short* __restrict__ wt3, short* __restrict__ wt4,
                 short* __restrict__ wt5, int* __restrict__ counts)
{
    const int gid = blockIdx.x * 256 + threadIdx.x;
    for (int c = gid; c < NTILES2 * NSUB * CSTRIDE; c += 65536) counts[c] = 0;
    for (int e = gid; e < 163840; e += 65536) {
        if (e < 32768) {                      // w3f[k][n] (128x256) -> wt3[n*128+k]
            const int k = e >> 8, n = e & 255;
            wt3[n * 128 + k] = f2bf(w3f[e]);
        } else if (e < 98304) {               // fw1f[k][n] (256x256) -> wt4[n*256+k]
            const int e2 = e - 32768;
            const int k = e2 >> 8, n = e2 & 255;
            wt4[n * 256 + k] = f2bf(fw1f[e2]);
        } else {                              // fw2f[k][n] (256x256) -> wt5[n*256+k]
            const int e2 = e - 98304;
            const int k = e2 >> 8, n = e2 & 255;
            wt5[n * 256 + k] = f2bf(fw2f[e2]);
        }
    }
}

// ---------------------------------------------------------------------------
// MFMA accumulate, 8-wave MLP version, full-layer weight preload.
// ---------------------------------------------------------------------------
template<int K>
__device__ __forceinline__ void mfma_acc(const short* __restrict__ wt,
                                         const float* actIn, f32x4 (&acc)[2],
                                         int wv_, int quad, int ln15)
{
    bf16x8 wreg[K / 16];                      // K=256: 16 x 4 VGPR = 64 VGPR
#pragma unroll
    for (int ks = 0; ks < K / 32; ++ks) {
        const int kb = ks * 32 + quad * 8;
#pragma unroll
        for (int tt = 0; tt < 2; ++tt) {
            const int n0 = (wv_ * 2 + tt) * 16;
            wreg[ks * 2 + tt] = *(const bf16x8*)&wt[(size_t)(n0 + ln15) * K + kb];
        }
    }
#pragma unroll
    for (int ks = 0; ks < K / 32; ++ks) {
        const int kb = ks * 32 + quad * 8;
        const float4 a0 = *(const float4*)&actIn[ln15 * SA + kb];
        const float4 a1 = *(const float4*)&actIn[ln15 * SA + kb + 4];
        bf16x8 af = { f2bf(a0.x), f2bf(a0.y), f2bf(a0.z), f2bf(a0.w),
                      f2bf(a1.x), f2bf(a1.y), f2bf(a1.z), f2bf(a1.w) };
#pragma unroll
        for (int tt = 0; tt < 2; ++tt)
            acc[tt] = __builtin_amdgcn_mfma_f32_16x16x32_bf16(af, wreg[ks * 2 + tt],
                                                              acc[tt], 0, 0, 0);
    }
}

// ---------------------------------------------------------------------------
// Fused MLP + param/bin, 512 threads.
// ---------------------------------------------------------------------------
__global__ __launch_bounds__(512, 4)
void pb_mlp_kernel(const float* __restrict__ g, const float* __restrict__ intr,
                   const float* __restrict__ w1, const float* __restrict__ b1,
                   const float* __restrict__ w2, const float* __restrict__ b2,
                   const short* __restrict__ wt3, const float* __restrict__ b3,
                   const short* __restrict__ wt4, const float* __restrict__ fb1,
                   const short* __restrict__ wt5, const float* __restrict__ fb2,
                   ushort_t* __restrict__ ftb,
                   float* __restrict__ pp, int* __restrict__ counts,
                   ushort_t* __restrict__ lists)
{
    __shared__ __align__(16) float A_[16 * SA];
    __shared__ __align__(16) float Bb[16 * SA];
    const int tid = threadIdx.x;

    if (blockIdx.x < 256) {
        const int row0 = blockIdx.x * 16;
        const int lane = tid & 63;
        const int wv_  = tid >> 6;
        const int quad = lane >> 4;
        const int ln15 = lane & 15;

        if (tid < 224) {
            const int k = tid / 16, m = tid % 16;
            A_[m * SA + k] = g[(size_t)(row0 + m) * 14 + k];
        }
        __syncthreads();

        {   // L1: 14 -> 64, relu
            const int col = tid & 63;
            const int m0  = (tid >> 6) * 2;
            float acc[2];
            const float bv = b1[col];
            acc[0] = bv; acc[1] = bv;
#pragma unroll
            for (int k = 0; k < 14; ++k) {
                const float wv = w1[k * 64 + col];
                acc[0] = fmaf(A_[(m0 + 0) * SA + k], wv, acc[0]);
                acc[1] = fmaf(A_[(m0 + 1) * SA + k], wv, acc[1]);
            }
            Bb[(m0 + 0) * SA + col] = fmaxf(acc[0], 0.f);
            Bb[(m0 + 1) * SA + col] = fmaxf(acc[1], 0.f);
        }
        __syncthreads();

        {   // L2: 64 -> 128, relu
            const int col = tid & 127;
            const int m0  = (tid >> 7) * 4;
            float acc[4];
            const float bv = b2[col];
#pragma unroll
            for (int r = 0; r < 4; ++r) acc[r] = bv;
#pragma unroll 4
            for (int kq = 0; kq < 16; ++kq) {
                float wv[4];
#pragma unroll
                for (int jj = 0; jj < 4; ++jj) wv[jj] = w2[(4 * kq + jj) * 128 + col];
#pragma unroll
                for (int r = 0; r < 4; ++r) {
                    const float4 a4 = *(const float4*)&Bb[(m0 + r) * SA + 4 * kq];
                    acc[r] = fmaf(a4.x, wv[0], acc[r]);
                    acc[r] = fmaf(a4.y, wv[1], acc[r]);
                    acc[r] = fmaf(a4.z, wv[2], acc[r]);
                    acc[r] = fmaf(a4.w, wv[3], acc[r]);
                }
            }
#pragma unroll
            for (int r = 0; r < 4; ++r)
                A_[(m0 + r) * SA + col] = fmaxf(acc[r], 0.f);
        }
        __syncthreads();

        {   // L3: 128 -> 256 MFMA
            f32x4 acc[2] = {{0,0,0,0},{0,0,0,0}};
            mfma_acc<128>(wt3, A_, acc, wv_, quad, ln15);
            __syncthreads();
#pragma unroll
            for (int tt = 0; tt < 2; ++tt) {
                const int n = (wv_ * 2 + tt) * 16 + ln15;
                const float bv = b3[n];
#pragma unroll
                for (int r = 0; r < 4; ++r)
                    Bb[(quad * 4 + r) * SA + n] = acc[tt][r] + bv;
            }
        }
        __syncthreads();

        {   // L4: 256 -> 256 MFMA, relu
            f32x4 acc[2] = {{0,0,0,0},{0,0,0,0}};
            mfma_acc<256>(wt4, Bb, acc, wv_, quad, ln15);
            __syncthreads();
#pragma unroll
            for (int tt = 0; tt < 2; ++tt) {
                const int n = (wv_ * 2 + tt) * 16 + ln15;
                const float bv = fb1[n];
#pragma unroll
                for (int r = 0; r < 4; ++r)
                    A_[(quad * 4 + r) * SA + n] = fmaxf(acc[tt][r] + bv, 0.f);
            }
        }
        __syncthreads();

        {   // L5: 256 -> 256 MFMA -> global bf16
            f32x4 acc[2] = {{0,0,0,0},{0,0,0,0}};
            mfma_acc<256>(wt5, A_, acc, wv_, quad, ln15);
#pragma unroll
            for (int tt = 0; tt < 2; ++tt) {
                const int n = (wv_ * 2 + tt) * 16 + ln15;
                const float bv = fb2[n];
#pragma unroll
                for (int r = 0; r < 4; ++r)
                    ftb[(size_t)(row0 + quad * 4 + r) * 256 + n] =
                        (ushort_t)f2bf(acc[tt][r] + bv);
            }
        }
        return;
    }

    // ================= param + bin role (2-row bands) =================
    const int sub = (blockIdx.x - 256) & (NSUB - 1);   // counter shard for this block
    const int i = (blockIdx.x - 256) * 16 + (tid >> 5);
    const int j = tid & 31;
    const float* gi = g + (size_t)i * 14;
    const float x = gi[0], y = gi[1], z = gi[2];
    const float s5 = gi[5], s6 = gi[6], wv = gi[12];
    const float k00 = intr[0], k01 = intr[1], k02 = intr[2];
    const float k10 = intr[3], k11 = intr[4], k12 = intr[5];
    const float k20 = intr[6], k21 = intr[7], k22 = intr[8];
    const float projx = k00 * x + k01 * y + k02 * z;
    const float projy = k10 * x + k11 * y + k12 * z;
    const float projz = k20 * x + k21 * y + k22 * z;
    const float inv = 1.f / (projz + 1e-6f);
    const float scale_x = (float)W_ / k02 * 0.5f;
    const float scale_y = (float)H_ / k12 * 0.5f;
    const float px = projx * inv * scale_x;
    const float py = projy * inv * scale_y;
    const bool valid = z > 0.1f;
    const bool inb = (px >= 0.f) && (px < (float)W_) && (py >= 0.f) && (py < (float)H_);
    const bool mask = valid && inb;
    const float sx = fmaxf(s5 * scale_x, 1.f);
    const float sy = fmaxf(s6 * scale_y, 1.f);
    if (j == 0) {
        float4* o = (float4*)(pp + (size_t)i * 8);
        o[0] = make_float4(px, py, 1.f / sx, 1.f / sy);
        o[1] = make_float4(wv, 0.5f * (sx + sy), 0.f, 0.f);
    }
    if (!mask) return;
    const float rx = 3.f * sx, ry = 3.f * sy;
    const int ymin = max(0, (int)floorf(py - ry));
    const int ymax = min(H_ - 1, (int)ceilf(py + ry));
    const int bmin = ymin >> 1, bmax = ymax >> 1;
    const int band = bmin + j;
    if (band > bmax) return;
    const int tmin = max(0, (int)floorf((px - rx - (float)(TW - 1)) * (1.f / TW)));
    const int tmax = min(NTX - 1, (int)ceilf((px + rx) * (1.f / TW)));
    const int b = i / N_, n = i - b * N_;
    for (int t = tmin; t <= tmax; ++t) {
        const int tile = (b * NYB + band) * NTX + t;
        const int slot = atomicAdd(&counts[(tile * NSUB + sub) * CSTRIDE], 1);
        if (slot < SUBCAP)
            lists[((size_t)tile * NSUB + sub) * SUBCAP + slot] = (ushort_t)n;
    }
}

// ---------------------------------------------------------------------------
// Splat with MFMA phase B. Block = 16px x 2row tile; chunks of K=32.
// Sub-lists concatenated into LDS up front (list reads become LDS broadcast).
// ---------------------------------------------------------------------------
__global__ __launch_bounds__(256)
void splat_kernel(const float* __restrict__ pp, const ushort_t* __restrict__ lists,
                  const int* __restrict__ counts, const ushort_t* __restrict__ ftb,
                  float* __restrict__ out)
{
    __shared__ __align__(16) ushort_t feats_t[2][256 * FS];  // 2 x 20 KB
    __shared__ __align__(16) ushort_t gw_t[2][32 * FS];      // 2 x 2.5 KB
    __shared__ __align__(16) ushort_t list_s[NSUB * SUBCAP]; // 4 KB

    const int tid = threadIdx.x;
    // center-first tile decode
    const int qb = blockIdx.x;
    const int b  = qb & 1;
    const int t_ = qb >> 1;
    const int yr = t_ / NTX, xr = t_ % NTX;
    const int yh = (yr + 1) >> 1;
    const int yb = (yr & 1) ? (16 - yh) : (16 + yh);
    const int xh = (xr + 1) >> 1;
    const int txi = (xr & 1) ? (5 - xh) : (5 + xh);
    const int tb  = (b * NYB + yb) * NTX + txi;
    const int y0 = yb * 2, x0 = txi * TW;

    // ---- gather sub-lists -> contiguous LDS list ----
    int tot = 0;
#pragma unroll
    for (int s = 0; s < NSUB; ++s) {
        const int cs = min(counts[(tb * NSUB + s) * CSTRIDE], SUBCAP);
        const ushort_t* src = lists + ((size_t)tb * NSUB + s) * SUBCAP;
        for (int k = tid; k < cs; k += 256) list_s[tot + k] = src[k];
        tot += cs;
    }
    __syncthreads();
    const int cnt = tot;

    const ushort_t* mylist = list_s;
    const int gs   = tid >> 5;            // phase A gaussian sub-slot (0..7)
    const int px32 = tid & 31;            // phase A pixel (row*16+x)
    const float fy = (float)(y0 + (px32 >> 4));
    const float fx = (float)(x0 + (px32 & 15));
    const int chg = tid >> 4;             // stage: ch group (0..15), 16 ch each
    const int qp  = tid & 15;             // stage: q pair (0..15)
    const int bN = b * N_;
    const int lane = tid & 63;
    const int wv_  = tid >> 6;
    const int quad = lane >> 4;
    const int ln15 = lane & 15;

    f32x4 acc[2][4];
#pragma unroll
    for (int mt = 0; mt < 2; ++mt)
#pragma unroll
        for (int nt = 0; nt < 4; ++nt) acc[mt][nt] = (f32x4){0.f, 0.f, 0.f, 0.f};
    float densp = 0.f, uncp = 0.f;

    uint4 ra0, ra1, rb0, rb1;             // staged 16ch x 2 rows
    const int nchunks = (cnt + 31) >> 5;

    if (cnt > 0) {
        const float4* pv = (const float4*)pp;
        {   // prefetch chunk 0 rows
            const int n0 = mylist[min(2 * qp, cnt - 1)];
            const int n1 = mylist[min(2 * qp + 1, cnt - 1)];
            const uint4* f0 = (const uint4*)(ftb + ((size_t)(bN + n0) << 8) + chg * 16);
            const uint4* f1 = (const uint4*)(ftb + ((size_t)(bN + n1) << 8) + chg * 16);
            ra0 = f0[0]; ra1 = f0[1];
            rb0 = f1[0]; rb1 = f1[1];
        }
        for (int c = 0; c < nchunks; ++c) {
            const int buf = c & 1;
            // ---- phase A: 4 gw per thread -> gw_t[buf] (bf16) ----
#pragma unroll
            for (int jj = 0; jj < 4; ++jj) {
                const int q = 8 * jj + gs;
                const int qi = c * 32 + q;
                const int n = mylist[min(qi, cnt - 1)];
                const float4 e0 = pv[(size_t)(bN + n) * 2 + 0];
                const float4 e1 = pv[(size_t)(bN + n) * 2 + 1];
                const float dyn = (fy - e0.y) * e0.w;
                const float dxn = (fx - e0.x) * e0.z;
                const float dist = dyn * dyn + dxn * dxn;
                float gv = 0.f;
                if (dist < 9.f) gv = __expf(-0.5f * dist) * e1.x;
                if (qi >= cnt) gv = 0.f;
                gw_t[buf][px32 * FS + q] = (ushort_t)f2bf(gv);
                densp += gv;
                uncp  += gv * e1.y;
            }
            // ---- stage: transpose regs -> feats_t[buf][ch][k] ----
            {
                uint* dst = (uint*)&feats_t[buf][0];
#pragma unroll
                for (int jj = 0; jj < 4; ++jj) {
                    const uint u0 = (&ra0.x)[jj], v0 = (&rb0.x)[jj];
                    const int ch = chg * 16 + 2 * jj;
                    dst[ch * (FS / 2) + qp]       = (u0 & 0xffffu) | (v0 << 16);
                    dst[(ch + 1) * (FS / 2) + qp] = (u0 >> 16) | (v0 & 0xffff0000u);
                }
#pragma unroll
                for (int jj = 0; jj < 4; ++jj) {
                    const uint u0 = (&ra1.x)[jj], v0 = (&rb1.x)[jj];
                    const int ch = chg * 16 + 8 + 2 * jj;
                    dst[ch * (FS / 2) + qp]       = (u0 & 0xffffu) | (v0 << 16);
                    dst[(ch + 1) * (FS / 2) + qp] = (u0 >> 16) | (v0 & 0xffff0000u);
                }
            }
            __syncthreads();
            // ---- prefetch chunk c+1 rows (overlaps phase B) ----
            if (c + 1 < nchunks) {
                const int q0 = (c + 1) * 32 + 2 * qp;
                const int n0 = mylist[min(q0, cnt - 1)];
                const int n1 = mylist[min(q0 + 1, cnt - 1)];
                const uint4* f0 = (const uint4*)(ftb + ((size_t)(bN + n0) << 8) + chg * 16);
                const uint4* f1 = (const uint4*)(ftb + ((size_t)(bN + n1) << 8) + chg * 16);
                ra0 = f0[0]; ra1 = f0[1];
                rb0 = f1[0]; rb1 = f1[1];
            }
            // ---- phase B: 8 MFMA per wave ----
            bf16x8 af[2];
#pragma unroll
            for (int mt = 0; mt < 2; ++mt)
                af[mt] = *(const bf16x8*)&gw_t[buf][(mt * 16 + ln15) * FS + quad * 8];
#pragma unroll
            for (int nt = 0; nt < 4; ++nt) {
                const int ch0 = wv_ * 64 + nt * 16;
                const bf16x8 bf = *(const bf16x8*)&feats_t[buf][(ch0 + ln15) * FS + quad * 8];
                acc[0][nt] = __builtin_amdgcn_mfma_f32_16x16x32_bf16(af[0], bf, acc[0][nt], 0, 0, 0);
                acc[1][nt] = __builtin_amdgcn_mfma_f32_16x16x32_bf16(af[1], bf, acc[1][nt], 0, 0, 0);
            }
        }
    }

    // ---- density / uncertainty reduction over 8 gs-groups ----
    __syncthreads();
    float* red_d = (float*)&feats_t[0][0];   // 8 x 36
    float* red_u = red_d + 8 * 36;
    red_d[gs * 36 + px32] = densp;
    red_u[gs * 36 + px32] = uncp;
    __syncthreads();
    for (int s = 4; s > 0; s >>= 1) {
        if (gs < s) {
            red_d[gs * 36 + px32] += red_d[(gs + s) * 36 + px32];
            red_u[gs * 36 + px32] += red_u[(gs + s) * 36 + px32];
        }
        __syncthreads();
    }

    if (tid < 32) {
        const int yy = y0 + (tid >> 4), xx = x0 + (tid & 15);
        const size_t pix = ((size_t)b * H_ + yy) * W_ + xx;
        float* unc_o = out + (size_t)B_ * C_ * H_ * W_;
        float* den_o = unc_o + (size_t)B_ * H_ * W_;
        const float d = fmaxf(red_d[tid], 1e-6f);
        unc_o[pix] = red_u[tid] / d;
        den_o[pix] = d;
    }

    // ---- feature stores: lane = ch (ln15), 4 consecutive x per acc ----
#pragma unroll
    for (int mt = 0; mt < 2; ++mt) {
        const int pxb = mt * 16 + quad * 4;
        float rinv[4];
#pragma unroll
        for (int r = 0; r < 4; ++r)
            rinv[r] = 1.f / fmaxf(red_d[pxb + r], 1e-6f);
        const int yy = y0 + mt;
#pragma unroll
        for (int nt = 0; nt < 4; ++nt) {
            const int ch = wv_ * 64 + nt * 16 + ln15;
            float4 v;
            v.x = acc[mt][nt][0] * rinv[0];
            v.y = acc[mt][nt][1] * rinv[1];
            v.z = acc[mt][nt][2] * rinv[2];
            v.w = acc[mt][nt][3] * rinv[3];
            *(float4*)(out + (((size_t)b * C_ + ch) * H_ + yy) * W_
                       + x0 + quad * 4) = v;
        }
    }
}

// ---------------------------------------------------------------------------
extern "C" void kernel_launch(void* const* d_in, const int* in_sizes, int n_in,
                              void* d_out, int out_size, void* d_ws, size_t ws_size,
                              hipStream_t stream)
{
    const float* g    = (const float*)d_in[0];
    const float* intr = (const float*)d_in[1];
    const float* w1   = (const float*)d_in[2];
    const float* b1   = (const float*)d_in[3];
    const float* w2   = (const float*)d_in[4];
    const float* b2   = (const float*)d_in[5];
    const float* w3   = (const float*)d_in[6];
    const float* b3   = (const float*)d_in[7];
    const float* fw1  = (const float*)d_in[8];
    const float* fb1  = (const float*)d_in[9];
    const float* fw2  = (const float*)d_in[10];
    const float* fb2  = (const float*)d_in[11];

    char* base = (char*)d_ws;
    const int rows = B_ * N_;                                // 4096
    ushort_t* ftb = (ushort_t*)base;                         // 2 MB bf16 [row][ch]
    float* pp     = (float*)(base + (size_t)rows * C_ * 2);  // 128 KB
    int*   counts = (int*)(pp + (size_t)8 * rows);           // 704*8 counters, 64B apart
    ushort_t* lists = (ushort_t*)(counts + NTILES2 * NSUB * CSTRIDE); // 2.9 MB
    short* wt3    = (short*)(lists + (size_t)NTILES2 * NSUB * SUBCAP);
    short* wt4    = wt3 + 128 * 256;
    short* wt5    = wt4 + 256 * 256;

    prep_kernel<<<dim3(256), dim3(256), 0, stream>>>(w3, fw1, fw2, wt3, wt4, wt5, counts);
    pb_mlp_kernel<<<dim3(512), dim3(512), 0, stream>>>(
        g, intr, w1, b1, w2, b2, wt3, b3, wt4, fb1, wt5, fb2, ftb, pp, counts, lists);
    splat_kernel<<<dim3(NTILES2), dim3(256), 0, stream>>>(pp, lists, counts, ftb, (float*)d_out);
}

// Round 5
// 128.763 us; speedup vs baseline: 2.4531x; 1.0398x over previous
//
#include <hip/hip_runtime.h>
#include <cstdint>
#include <cstddef>

#define B_ 2
#define N_ 2048
#define C_ 256
#define H_ 64
#define W_ 176
#define TW 16
#define NTX 11                    // 176/16 tiles per row
#define NYB 32                    // 2-row bands
#define NTILES2 (B_*NYB*NTX)      // 704 tiles (16px x 2row)
#define NSUB 8                    // per-tile counter/list shards
#define SUBCAP 256                // per-shard list cap
#define SA 260                    // mlp act LDS stride (floats)
#define FS 40                     // feats_t / gw_t row stride (ushort) = 80 B
#define CSTRIDE 16                // counters padded to 1 per 64B line

typedef unsigned short ushort_t;
typedef short bf16x8 __attribute__((ext_vector_type(8)));
typedef float f32x4  __attribute__((ext_vector_type(4)));

__device__ __forceinline__ short f2bf(float f)   // RNE fp32->bf16
{
    unsigned u = __float_as_uint(f);
    return (short)((u + 0x7FFFu + ((u >> 16) & 1u)) >> 16);
}

// ---------------------------------------------------------------------------
// prep: zero tile counters + fp32->bf16 transposed weight convert.
// ---------------------------------------------------------------------------
__global__ __launch_bounds__(256)
void prep_kernel(const float* __restrict__ w3f, const float* __restrict__ fw1f,
                 const float* __restrict__ fw2f,
                 short* __restrict__ wt3, short* __restrict__ wt4,
                 short* __restrict__ wt5, int* __restrict__ counts)
{
    const int gid = blockIdx.x * 256 + threadIdx.x;
    for (int c = gid; c < NTILES2 * NSUB * CSTRIDE; c += 65536) counts[c] = 0;
    for (int e = gid; e < 163840; e += 65536) {
        if (e < 32768) {                      // w3f[k][n] (128x256) -> wt3[n*128+k]
            const int k = e >> 8, n = e & 255;
            wt3[n * 128 + k] = f2bf(w3f[e]);
        } else if (e < 98304) {               // fw1f[k][n] (256x256) -> wt4[n*256+k]
            const int e2 = e - 32768;
            const int k = e2 >> 8, n = e2 & 255;
            wt4[n * 256 + k] = f2bf(fw1f[e2]);
        } else {                              // fw2f[k][n] (256x256) -> wt5[n*256+k]
            const int e2 = e - 98304;
            const int k = e2 >> 8, n = e2 & 255;
            wt5[n * 256 + k] = f2bf(fw2f[e2]);
        }
    }
}

// ---------------------------------------------------------------------------
// MFMA accumulate, 8-wave MLP version, full-layer weight preload.
// ---------------------------------------------------------------------------
template<int K>
__device__ __forceinline__ void mfma_acc(const short* __restrict__ wt,
                                         const float* actIn, f32x4 (&acc)[2],
                                         int wv_, int quad, int ln15)
{
    bf16x8 wreg[K / 16];
#pragma unroll
    for (int ks = 0; ks < K / 32; ++ks) {
        const int kb = ks * 32 + quad * 8;
#pragma unroll
        for (int tt = 0; tt < 2; ++tt) {
            const int n0 = (wv_ * 2 + tt) * 16;
            wreg[ks * 2 + tt] = *(const bf16x8*)&wt[(size_t)(n0 + ln15) * K + kb];
        }
    }
#pragma unroll
    for (int ks = 0; ks < K / 32; ++ks) {
        const int kb = ks * 32 + quad * 8;
        const float4 a0 = *(const float4*)&actIn[ln15 * SA + kb];
        const float4 a1 = *(const float4*)&actIn[ln15 * SA + kb + 4];
        bf16x8 af = { f2bf(a0.x), f2bf(a0.y), f2bf(a0.z), f2bf(a0.w),
                      f2bf(a1.x), f2bf(a1.y), f2bf(a1.z), f2bf(a1.w) };
#pragma unroll
        for (int tt = 0; tt < 2; ++tt)
            acc[tt] = __builtin_amdgcn_mfma_f32_16x16x32_bf16(af, wreg[ks * 2 + tt],
                                                              acc[tt], 0, 0, 0);
    }
}

// ---------------------------------------------------------------------------
// Fused MLP + param/bin, 512 threads.
// ---------------------------------------------------------------------------
__global__ __launch_bounds__(512, 4)
void pb_mlp_kernel(const float* __restrict__ g, const float* __restrict__ intr,
                   const float* __restrict__ w1, const float* __restrict__ b1,
                   const float* __restrict__ w2, const float* __restrict__ b2,
                   const short* __restrict__ wt3, const float* __restrict__ b3,
                   const short* __restrict__ wt4, const float* __restrict__ fb1,
                   const short* __restrict__ wt5, const float* __restrict__ fb2,
                   ushort_t* __restrict__ ftb,
                   float* __restrict__ pp, int* __restrict__ counts,
                   ushort_t* __restrict__ lists)
{
    __shared__ __align__(16) float A_[16 * SA];
    __shared__ __align__(16) float Bb[16 * SA];
    const int tid = threadIdx.x;

    if (blockIdx.x < 256) {
        const int row0 = blockIdx.x * 16;
        const int lane = tid & 63;
        const int wv_  = tid >> 6;
        const int quad = lane >> 4;
        const int ln15 = lane & 15;

        if (tid < 224) {
            const int k = tid / 16, m = tid % 16;
            A_[m * SA + k] = g[(size_t)(row0 + m) * 14 + k];
        }
        __syncthreads();

        {   // L1: 14 -> 64, relu
            const int col = tid & 63;
            const int m0  = (tid >> 6) * 2;
            float acc[2];
            const float bv = b1[col];
            acc[0] = bv; acc[1] = bv;
#pragma unroll
            for (int k = 0; k < 14; ++k) {
                const float wv = w1[k * 64 + col];
                acc[0] = fmaf(A_[(m0 + 0) * SA + k], wv, acc[0]);
                acc[1] = fmaf(A_[(m0 + 1) * SA + k], wv, acc[1]);
            }
            Bb[(m0 + 0) * SA + col] = fmaxf(acc[0], 0.f);
            Bb[(m0 + 1) * SA + col] = fmaxf(acc[1], 0.f);
        }
        __syncthreads();

        {   // L2: 64 -> 128, relu
            const int col = tid & 127;
            const int m0  = (tid >> 7) * 4;
            float acc[4];
            const float bv = b2[col];
#pragma unroll
            for (int r = 0; r < 4; ++r) acc[r] = bv;
#pragma unroll 4
            for (int kq = 0; kq < 16; ++kq) {
                float wv[4];
#pragma unroll
                for (int jj = 0; jj < 4; ++jj) wv[jj] = w2[(4 * kq + jj) * 128 + col];
#pragma unroll
                for (int r = 0; r < 4; ++r) {
                    const float4 a4 = *(const float4*)&Bb[(m0 + r) * SA + 4 * kq];
                    acc[r] = fmaf(a4.x, wv[0], acc[r]);
                    acc[r] = fmaf(a4.y, wv[1], acc[r]);
                    acc[r] = fmaf(a4.z, wv[2], acc[r]);
                    acc[r] = fmaf(a4.w, wv[3], acc[r]);
                }
            }
#pragma unroll
            for (int r = 0; r < 4; ++r)
                A_[(m0 + r) * SA + col] = fmaxf(acc[r], 0.f);
        }
        __syncthreads();

        {   // L3: 128 -> 256 MFMA
            f32x4 acc[2] = {{0,0,0,0},{0,0,0,0}};
            mfma_acc<128>(wt3, A_, acc, wv_, quad, ln15);
            __syncthreads();
#pragma unroll
            for (int tt = 0; tt < 2; ++tt) {
                const int n = (wv_ * 2 + tt) * 16 + ln15;
                const float bv = b3[n];
#pragma unroll
                for (int r = 0; r < 4; ++r)
                    Bb[(quad * 4 + r) * SA + n] = acc[tt][r] + bv;
            }
        }
        __syncthreads();

        {   // L4: 256 -> 256 MFMA, relu
            f32x4 acc[2] = {{0,0,0,0},{0,0,0,0}};
            mfma_acc<256>(wt4, Bb, acc, wv_, quad, ln15);
            __syncthreads();
#pragma unroll
            for (int tt = 0; tt < 2; ++tt) {
                const int n = (wv_ * 2 + tt) * 16 + ln15;
                const float bv = fb1[n];
#pragma unroll
                for (int r = 0; r < 4; ++r)
                    A_[(quad * 4 + r) * SA + n] = fmaxf(acc[tt][r] + bv, 0.f);
            }
        }
        __syncthreads();

        {   // L5: 256 -> 256 MFMA -> global bf16
            f32x4 acc[2] = {{0,0,0,0},{0,0,0,0}};
            mfma_acc<256>(wt5, A_, acc, wv_, quad, ln15);
#pragma unroll
            for (int tt = 0; tt < 2; ++tt) {
                const int n = (wv_ * 2 + tt) * 16 + ln15;
                const float bv = fb2[n];
#pragma unroll
                for (int r = 0; r < 4; ++r)
                    ftb[(size_t)(row0 + quad * 4 + r) * 256 + n] =
                        (ushort_t)f2bf(acc[tt][r] + bv);
            }
        }
        return;
    }

    // ================= param + bin role (2-row bands) =================
    const int sub = (blockIdx.x - 256) & (NSUB - 1);
    const int i = (blockIdx.x - 256) * 16 + (tid >> 5);
    const int j = tid & 31;
    const float* gi = g + (size_t)i * 14;
    const float x = gi[0], y = gi[1], z = gi[2];
    const float s5 = gi[5], s6 = gi[6], wv = gi[12];
    const float k00 = intr[0], k01 = intr[1], k02 = intr[2];
    const float k10 = intr[3], k11 = intr[4], k12 = intr[5];
    const float k20 = intr[6], k21 = intr[7], k22 = intr[8];
    const float projx = k00 * x + k01 * y + k02 * z;
    const float projy = k10 * x + k11 * y + k12 * z;
    const float projz = k20 * x + k21 * y + k22 * z;
    const float inv = 1.f / (projz + 1e-6f);
    const float scale_x = (float)W_ / k02 * 0.5f;
    const float scale_y = (float)H_ / k12 * 0.5f;
    const float px = projx * inv * scale_x;
    const float py = projy * inv * scale_y;
    const bool valid = z > 0.1f;
    const bool inb = (px >= 0.f) && (px < (float)W_) && (py >= 0.f) && (py < (float)H_);
    const bool mask = valid && inb;
    const float sx = fmaxf(s5 * scale_x, 1.f);
    const float sy = fmaxf(s6 * scale_y, 1.f);
    if (j == 0) {
        float4* o = (float4*)(pp + (size_t)i * 8);
        o[0] = make_float4(px, py, 1.f / sx, 1.f / sy);
        o[1] = make_float4(wv, 0.5f * (sx + sy), 0.f, 0.f);
    }
    if (!mask) return;
    const float rx = 3.f * sx, ry = 3.f * sy;
    const int ymin = max(0, (int)floorf(py - ry));
    const int ymax = min(H_ - 1, (int)ceilf(py + ry));
    const int bmin = ymin >> 1, bmax = ymax >> 1;
    const int band = bmin + j;
    if (band > bmax) return;
    const int tmin = max(0, (int)floorf((px - rx - (float)(TW - 1)) * (1.f / TW)));
    const int tmax = min(NTX - 1, (int)ceilf((px + rx) * (1.f / TW)));
    const int b = i / N_, n = i - b * N_;
    for (int t = tmin; t <= tmax; ++t) {
        const int tile = (b * NYB + band) * NTX + t;
        const int slot = atomicAdd(&counts[(tile * NSUB + sub) * CSTRIDE], 1);
        if (slot < SUBCAP)
            lists[((size_t)tile * NSUB + sub) * SUBCAP + slot] = (ushort_t)n;
    }
}

// ---------------------------------------------------------------------------
// Splat, 512 threads / 8 waves: per-chunk phases halved vs 256-thread version.
// Phase A: 2 gaussians/thread. Stage: 8 ch x 2 rows/thread. Phase B: 4 MFMA
// per wave (2 mt x 2 nt, ch0 = wv*32 + nt*16). Sub-list gather with count
// prefetch (breaks the 8-deep dependent-load chain).
// ---------------------------------------------------------------------------
__global__ __launch_bounds__(512)
void splat_kernel(const float* __restrict__ pp, const ushort_t* __restrict__ lists,
                  const int* __restrict__ counts, const ushort_t* __restrict__ ftb,
                  float* __restrict__ out)
{
    __shared__ __align__(16) ushort_t feats_t[2][256 * FS];  // 2 x 20 KB
    __shared__ __align__(16) ushort_t gw_t[2][32 * FS];      // 2 x 2.5 KB
    __shared__ __align__(16) ushort_t list_s[NSUB * SUBCAP]; // 4 KB

    const int tid = threadIdx.x;
    // center-first tile decode
    const int qb = blockIdx.x;
    const int b  = qb & 1;
    const int t_ = qb >> 1;
    const int yr = t_ / NTX, xr = t_ % NTX;
    const int yh = (yr + 1) >> 1;
    const int yb = (yr & 1) ? (16 - yh) : (16 + yh);
    const int xh = (xr + 1) >> 1;
    const int txi = (xr & 1) ? (5 - xh) : (5 + xh);
    const int tb  = (b * NYB + yb) * NTX + txi;
    const int y0 = yb * 2, x0 = txi * TW;

    // ---- gather sub-lists -> contiguous LDS list (counts prefetched) ----
    int cs[NSUB];
#pragma unroll
    for (int s = 0; s < NSUB; ++s)
        cs[s] = min(counts[(tb * NSUB + s) * CSTRIDE], SUBCAP);
    int off[NSUB];
    int tot = 0;
#pragma unroll
    for (int s = 0; s < NSUB; ++s) { off[s] = tot; tot += cs[s]; }
#pragma unroll
    for (int s = 0; s < NSUB; ++s) {
        const ushort_t* src = lists + ((size_t)tb * NSUB + s) * SUBCAP;
        if (tid < cs[s]) list_s[off[s] + tid] = src[tid];   // cs<=256<512: one shot
    }
    __syncthreads();
    const int cnt = tot;

    const ushort_t* mylist = list_s;
    const int gs   = tid >> 5;            // phase A gaussian sub-slot (0..15)
    const int px32 = tid & 31;            // phase A pixel (row*16+x)
    const float fy = (float)(y0 + (px32 >> 4));
    const float fx = (float)(x0 + (px32 & 15));
    const int chg = tid >> 4;             // stage: ch group (0..31), 8 ch each
    const int qp  = tid & 15;             // stage: q pair (0..15)
    const int bN = b * N_;
    const int lane = tid & 63;
    const int wv_  = tid >> 6;            // 0..7
    const int quad = lane >> 4;
    const int ln15 = lane & 15;

    f32x4 acc[2][2];
#pragma unroll
    for (int mt = 0; mt < 2; ++mt)
#pragma unroll
        for (int nt = 0; nt < 2; ++nt) acc[mt][nt] = (f32x4){0.f, 0.f, 0.f, 0.f};
    float densp = 0.f, uncp = 0.f;

    uint4 ra0, rb0;                       // staged 8ch x 2 rows
    const int nchunks = (cnt + 31) >> 5;

    if (cnt > 0) {
        const float4* pv = (const float4*)pp;
        {   // prefetch chunk 0 rows
            const int n0 = mylist[min(2 * qp, cnt - 1)];
            const int n1 = mylist[min(2 * qp + 1, cnt - 1)];
            ra0 = *(const uint4*)(ftb + ((size_t)(bN + n0) << 8) + chg * 8);
            rb0 = *(const uint4*)(ftb + ((size_t)(bN + n1) << 8) + chg * 8);
        }
        for (int c = 0; c < nchunks; ++c) {
            const int buf = c & 1;
            // ---- phase A: 2 gw per thread -> gw_t[buf] (bf16) ----
#pragma unroll
            for (int jj = 0; jj < 2; ++jj) {
                const int q = 16 * jj + gs;
                const int qi = c * 32 + q;
                const int n = mylist[min(qi, cnt - 1)];
                const float4 e0 = pv[(size_t)(bN + n) * 2 + 0];
                const float4 e1 = pv[(size_t)(bN + n) * 2 + 1];
                const float dyn = (fy - e0.y) * e0.w;
                const float dxn = (fx - e0.x) * e0.z;
                const float dist = dyn * dyn + dxn * dxn;
                float gv = 0.f;
                if (dist < 9.f) gv = __expf(-0.5f * dist) * e1.x;
                if (qi >= cnt) gv = 0.f;
                gw_t[buf][px32 * FS + q] = (ushort_t)f2bf(gv);
                densp += gv;
                uncp  += gv * e1.y;
            }
            // ---- stage: transpose regs -> feats_t[buf][ch][k] ----
            {
                uint* dst = (uint*)&feats_t[buf][0];
#pragma unroll
                for (int jj = 0; jj < 4; ++jj) {
                    const uint u0 = (&ra0.x)[jj], v0 = (&rb0.x)[jj];
                    const int ch = chg * 8 + 2 * jj;
                    dst[ch * (FS / 2) + qp]       = (u0 & 0xffffu) | (v0 << 16);
                    dst[(ch + 1) * (FS / 2) + qp] = (u0 >> 16) | (v0 & 0xffff0000u);
                }
            }
            __syncthreads();
            // ---- prefetch chunk c+1 rows (overlaps phase B) ----
            if (c + 1 < nchunks) {
                const int q0 = (c + 1) * 32 + 2 * qp;
                const int n0 = mylist[min(q0, cnt - 1)];
                const int n1 = mylist[min(q0 + 1, cnt - 1)];
                ra0 = *(const uint4*)(ftb + ((size_t)(bN + n0) << 8) + chg * 8);
                rb0 = *(const uint4*)(ftb + ((size_t)(bN + n1) << 8) + chg * 8);
            }
            // ---- phase B: 4 MFMA per wave ----
            bf16x8 af[2];
#pragma unroll
            for (int mt = 0; mt < 2; ++mt)
                af[mt] = *(const bf16x8*)&gw_t[buf][(mt * 16 + ln15) * FS + quad * 8];
#pragma unroll
            for (int nt = 0; nt < 2; ++nt) {
                const int ch0 = wv_ * 32 + nt * 16;
                const bf16x8 bf = *(const bf16x8*)&feats_t[buf][(ch0 + ln15) * FS + quad * 8];
                acc[0][nt] = __builtin_amdgcn_mfma_f32_16x16x32_bf16(af[0], bf, acc[0][nt], 0, 0, 0);
                acc[1][nt] = __builtin_amdgcn_mfma_f32_16x16x32_bf16(af[1], bf, acc[1][nt], 0, 0, 0);
            }
        }
    }

    // ---- density / uncertainty reduction over 16 gs-groups ----
    __syncthreads();
    float* red_d = (float*)&feats_t[0][0];   // 16 x 36
    float* red_u = red_d + 16 * 36;
    red_d[gs * 36 + px32] = densp;
    red_u[gs * 36 + px32] = uncp;
    __syncthreads();
    for (int s = 8; s > 0; s >>= 1) {
        if (gs < s) {
            red_d[gs * 36 + px32] += red_d[(gs + s) * 36 + px32];
            red_u[gs * 36 + px32] += red_u[(gs + s) * 36 + px32];
        }
        __syncthreads();
    }

    if (tid < 32) {
        const int yy = y0 + (tid >> 4), xx = x0 + (tid & 15);
        const size_t pix = ((size_t)b * H_ + yy) * W_ + xx;
        float* unc_o = out + (size_t)B_ * C_ * H_ * W_;
        float* den_o = unc_o + (size_t)B_ * H_ * W_;
        const float d = fmaxf(red_d[tid], 1e-6f);
        unc_o[pix] = red_u[tid] / d;
        den_o[pix] = d;
    }

    // ---- feature stores: lane = ch (ln15), 4 consecutive x per acc ----
#pragma unroll
    for (int mt = 0; mt < 2; ++mt) {
        const int pxb = mt * 16 + quad * 4;
        float rinv[4];
#pragma unroll
        for (int r = 0; r < 4; ++r)
            rinv[r] = 1.f / fmaxf(red_d[pxb + r], 1e-6f);
        const int yy = y0 + mt;
#pragma unroll
        for (int nt = 0; nt < 2; ++nt) {
            const int ch = wv_ * 32 + nt * 16 + ln15;
            float4 v;
            v.x = acc[mt][nt][0] * rinv[0];
            v.y = acc[mt][nt][1] * rinv[1];
            v.z = acc[mt][nt][2] * rinv[2];
            v.w = acc[mt][nt][3] * rinv[3];
            *(float4*)(out + (((size_t)b * C_ + ch) * H_ + yy) * W_
                       + x0 + quad * 4) = v;
        }
    }
}

// ---------------------------------------------------------------------------
extern "C" void kernel_launch(void* const* d_in, const int* in_sizes, int n_in,
                              void* d_out, int out_size, void* d_ws, size_t ws_size,
                              hipStream_t stream)
{
    const float* g    = (const float*)d_in[0];
    const float* intr = (const float*)d_in[1];
    const float* w1   = (const float*)d_in[2];
    const float* b1   = (const float*)d_in[3];
    const float* w2   = (const float*)d_in[4];
    const float* b2   = (const float*)d_in[5];
    const float* w3   = (const float*)d_in[6];
    const float* b3   = (const float*)d_in[7];
    const float* fw1  = (const float*)d_in[8];
    const float* fb1  = (const float*)d_in[9];
    const float* fw2  = (const float*)d_in[10];
    const float* fb2  = (const float*)d_in[11];

    char* base = (char*)d_ws;
    const int rows = B_ * N_;                                // 4096
    ushort_t* ftb = (ushort_t*)base;                         // 2 MB bf16 [row][ch]
    float* pp     = (float*)(base + (size_t)rows * C_ * 2);  // 128 KB
    int*   counts = (int*)(pp + (size_t)8 * rows);           // 704*8 counters, 64B apart
    ushort_t* lists = (ushort_t*)(counts + NTILES2 * NSUB * CSTRIDE); // 2.9 MB
    short* wt3    = (short*)(lists + (size_t)NTILES2 * NSUB * SUBCAP);
    short* wt4    = wt3 + 128 * 256;
    short* wt5    = wt4 + 256 * 256;

    prep_kernel<<<dim3(256), dim3(256), 0, stream>>>(w3, fw1, fw2, wt3, wt4, wt5, counts);
    pb_mlp_kernel<<<dim3(512), dim3(512), 0, stream>>>(
        g, intr, w1, b1, w2, b2, wt3, b3, wt4, fb1, wt5, fb2, ftb, pp, counts, lists);
    splat_kernel<<<dim3(NTILES2), dim3(512), 0, stream>>>(pp, lists, counts, ftb, (float*)d_out);
}